// Round 2
// baseline (3417.837 us; speedup 1.0000x reference)
//
#include <hip/hip_runtime.h>
#include <cstdint>
#include <cstddef>

// Problem constants (fixed by the reference).
constexpr int kN  = 25000;
constexpr int kE  = 400000;
constexpr int kD  = 64;
constexpr int kH  = 4;
constexpr int kHD = 256;       // H * DH

__device__ __forceinline__ float lrelu02(float x){ return x > 0.f ? x : 0.2f*x; }

// ---------------- CSR build ----------------
__global__ void k_deg(const int* __restrict__ col, int* __restrict__ deg){
  int i = blockIdx.x*256 + threadIdx.x;
  if (i < kE) atomicAdd(&deg[col[i]], 1);
}

__global__ void k_scan(const int* __restrict__ deg, int* __restrict__ col_start){
  __shared__ int lds[1024];
  __shared__ int carry_s;
  int t = threadIdx.x;
  if (t == 0) carry_s = 0;
  __syncthreads();
  for (int base = 0; base < kN; base += 1024){
    int v = (base + t < kN) ? deg[base + t] : 0;
    lds[t] = v; __syncthreads();
    for (int off = 1; off < 1024; off <<= 1){
      int add = (t >= off) ? lds[t - off] : 0;
      __syncthreads();
      lds[t] += add;
      __syncthreads();
    }
    int incl = lds[t];
    int carry = carry_s;
    if (base + t < kN) col_start[base + t] = carry + incl - v;
    __syncthreads();
    if (t == 0) carry_s = carry + lds[1023];
    __syncthreads();
  }
  if (t == 0) col_start[kN] = carry_s;
}

__global__ void k_fill(const int* __restrict__ col, const int* __restrict__ col_start,
                       int* __restrict__ fill, int* __restrict__ edge_ids){
  int i = blockIdx.x*256 + threadIdx.x;
  if (i < kE){
    int c = col[i];
    int p = atomicAdd(&fill[c], 1);
    edge_ids[col_start[c] + p] = i;
  }
}

// ---------------- initial embeddings ----------------
__global__ void k_x0(const float* __restrict__ nf, const float* __restrict__ W,
                     const float* __restrict__ b, float* __restrict__ x){
  int i = blockIdx.x*256 + threadIdx.x;
  if (i >= kN*kD) return;
  int n = i >> 6, d = i & 63;
  float acc = b[d];
#pragma unroll
  for (int k = 0; k < 16; k++) acc += nf[n*16 + k] * W[k*64 + d];
  x[i] = fmaxf(acc, 0.f);
}

__global__ void k_e0(const float* __restrict__ ea, const float* __restrict__ W,
                     const float* __restrict__ b, float* __restrict__ e){
  long long i = (long long)blockIdx.x*256 + threadIdx.x;
  if (i >= (long long)kE*kD) return;
  int n = (int)(i >> 6), d = (int)(i & 63);
  float acc = b[d];
#pragma unroll
  for (int k = 0; k < 4; k++) acc += ea[n*4 + k] * W[k*64 + d];
  e[i] = fmaxf(acc, 0.f);
}

// ---------------- per-layer: xl = x@Wl+bl, xr = x@Wr+br  (N x 256 each) ----------------
#define XLR_NPB 8
__global__ __launch_bounds__(256) void k_xlr(const float* __restrict__ x,
    const float* __restrict__ Wl, const float* __restrict__ bl,
    const float* __restrict__ Wr, const float* __restrict__ br,
    float* __restrict__ xl, float* __restrict__ xr){
  __shared__ float xs[XLR_NPB*64];
  int j = threadIdx.x;
  int n0 = blockIdx.x * XLR_NPB;
  for (int i = j; i < XLR_NPB*64; i += 256){
    int n = n0 + (i >> 6);
    xs[i] = (n < kN) ? x[(size_t)n*64 + (i & 63)] : 0.f;
  }
  __syncthreads();
  float accl[XLR_NPB], accr[XLR_NPB];
  float blv = bl[j], brv = br[j];
#pragma unroll
  for (int t = 0; t < XLR_NPB; t++){ accl[t] = blv; accr[t] = brv; }
  for (int k = 0; k < 64; k++){
    float wl = Wl[k*kHD + j], wr = Wr[k*kHD + j];
#pragma unroll
    for (int t = 0; t < XLR_NPB; t++){
      float xv = xs[t*64 + k];
      accl[t] += xv * wl; accr[t] += xv * wr;
    }
  }
#pragma unroll
  for (int t = 0; t < XLR_NPB; t++){
    int n = n0 + t;
    if (n < kN){ xl[(size_t)n*kHD + j] = accl[t]; xr[(size_t)n*kHD + j] = accr[t]; }
  }
}

// ---------------- fused per-layer GAT: e_loop + score + softmax + aggregate + LN -------
// Block = 256 threads; thread j owns We column j (64 regs). Grid-stride over
// target nodes; edges consumed in CSR order with online softmax, so xr is read
// once per node and xl rows are gathered exactly once (score + aggregation share).
#define GAT_CHUNK 8
__global__ __launch_bounds__(256) void k_gat_fused(
    const float* __restrict__ e, const float* __restrict__ xl,
    const float* __restrict__ xr,
    const int* __restrict__ row,
    const int* __restrict__ col_start, const int* __restrict__ edge_ids,
    const float* __restrict__ We, const float* __restrict__ att,
    const float* __restrict__ conv_b, const float* __restrict__ ln_g,
    const float* __restrict__ ln_b, float* __restrict__ x)
{
  int j = threadIdx.x;          // 0..255 : output column (head = j>>6)
  float w[64];
#pragma unroll
  for (int k = 0; k < 64; k++) w[k] = We[k*kHD + j];
  float attv = att[j];

  __shared__ float elds[GAT_CHUNK][64];
  __shared__ int   meta_r[GAT_CHUNK];
  __shared__ float out_lds[256];

  for (int n = blockIdx.x; n < kN; n += gridDim.x){
    int s0 = col_start[n], s1 = col_start[n+1];
    int deg = s1 - s0;
    float xr_j  = xr[(size_t)n*kHD + j];
    float xls_j = xl[(size_t)n*kHD + j];
    float m = -3.0e38f, s = 0.f, acc = 0.f;
    float esum = 0.f;                       // used by j<64 only

    for (int p0 = s0; p0 < s1; p0 += GAT_CHUNK){
      int cnt = min(GAT_CHUNK, s1 - p0);
      __syncthreads();                      // protect elds reuse
      if (j < GAT_CHUNK && p0 + j < s1){
        meta_r[j] = row[edge_ids[p0 + j]];
      }
      if (j < GAT_CHUNK*16){
        int t = j >> 4;
        if (p0 + t < s1){
          int eid = edge_ids[p0 + t];
          ((float4*)elds[t])[j & 15] = ((const float4*)(e + (size_t)eid*64))[j & 15];
        }
      }
      __syncthreads();
      // issue all xl gathers up front (static indices -> stays in VGPRs)
      float xlv[GAT_CHUNK];
#pragma unroll
      for (int t = 0; t < GAT_CHUNK; t++){
        if (t < cnt) xlv[t] = xl[(size_t)meta_r[t]*kHD + j];
      }
#pragma unroll
      for (int t = 0; t < GAT_CHUNK; t++){
        if (t >= cnt) break;
        const float4* ep = (const float4*)elds[t];
        float a0=0.f,a1=0.f,a2=0.f,a3=0.f;
#pragma unroll
        for (int k4 = 0; k4 < 16; k4++){
          float4 v = ep[k4];
          a0 += v.x*w[4*k4+0]; a1 += v.y*w[4*k4+1];
          a2 += v.z*w[4*k4+2]; a3 += v.w*w[4*k4+3];
        }
        float msg = (a0+a1)+(a2+a3) + xlv[t] + xr_j;
        float sc = lrelu02(msg) * attv;
#pragma unroll
        for (int off = 32; off; off >>= 1) sc += __shfl_xor(sc, off);
        if (sc > m){                        // wave-uniform branch
          float r0 = expf(m - sc);
          s *= r0; acc *= r0; m = sc;
        }
        float a = expf(sc - m);
        s += a; acc += a * xlv[t];
      }
      if (j < 64){
#pragma unroll
        for (int t = 0; t < GAT_CHUNK; t++){
          if (t < cnt) esum += elds[t][j];
        }
      }
    }

    // ---- self loop: e_loop = mean of staged rows ----
    __syncthreads();
    if (j < 64) elds[0][j] = esum * (1.f / (float)(deg > 0 ? deg : 1));
    __syncthreads();
    {
      const float4* ep = (const float4*)elds[0];
      float a0=0.f,a1=0.f,a2=0.f,a3=0.f;
#pragma unroll
      for (int k4 = 0; k4 < 16; k4++){
        float4 v = ep[k4];
        a0 += v.x*w[4*k4+0]; a1 += v.y*w[4*k4+1];
        a2 += v.z*w[4*k4+2]; a3 += v.w*w[4*k4+3];
      }
      float msg = (a0+a1)+(a2+a3) + xls_j + xr_j;
      float sc = lrelu02(msg) * attv;
#pragma unroll
      for (int off = 32; off; off >>= 1) sc += __shfl_xor(sc, off);
      if (sc > m){
        float r0 = expf(m - sc);
        s *= r0; acc *= r0; m = sc;
      }
      float a = expf(sc - m);
      s += a; acc += a * xls_j;
    }

    out_lds[j] = acc / s;
    __syncthreads();
    if (j < 64){
      float upd = (out_lds[j] + out_lds[64+j] + out_lds[128+j] + out_lds[192+j]) * 0.25f
                  + conv_b[j];
      float y = x[(size_t)n*64 + j] + upd;
      float mu = y;
#pragma unroll
      for (int off = 32; off; off >>= 1) mu += __shfl_xor(mu, off);
      mu *= (1.f/64.f);
      float diff = y - mu;
      float var = diff*diff;
#pragma unroll
      for (int off = 32; off; off >>= 1) var += __shfl_xor(var, off);
      var *= (1.f/64.f);
      float o = diff * rsqrtf(var + 1e-5f) * ln_g[j] + ln_b[j];
      x[(size_t)n*64 + j] = fmaxf(o, 0.f);
    }
    __syncthreads();                        // out_lds/elds safe for next node
  }
}

// ---------------- per-layer: P = x@W1a + b1, Q = x@W1b  (node-level split of edge MLP) --
#define PQ_NPB 16
__global__ __launch_bounds__(256) void k_pq(const float* __restrict__ x,
    const float* __restrict__ W1, const float* __restrict__ b1,
    float* __restrict__ P, float* __restrict__ Q){
  __shared__ float xs[PQ_NPB*64];
  int tid = threadIdx.x;
  int j = tid & 63;
  int s = tid >> 6;     // 0..3, each handles 4 nodes
  int n0 = blockIdx.x * PQ_NPB;
  for (int i = tid; i < PQ_NPB*64; i += 256){
    int n = n0 + (i >> 6);
    xs[i] = (n < kN) ? x[(size_t)n*64 + (i & 63)] : 0.f;
  }
  __syncthreads();
  float accP[4], accQ[4];
  float b1v = b1[j];
#pragma unroll
  for (int t = 0; t < 4; t++){ accP[t] = b1v; accQ[t] = 0.f; }
  for (int k = 0; k < 64; k++){
    float wa = W1[k*64 + j];          // rows 0..63  : x[row] part
    float wb = W1[(64 + k)*64 + j];   // rows 64..127: x[col] part
#pragma unroll
    for (int t = 0; t < 4; t++){
      float xv = xs[(s*4 + t)*64 + k];
      accP[t] += xv * wa; accQ[t] += xv * wb;
    }
  }
#pragma unroll
  for (int t = 0; t < 4; t++){
    int n = n0 + s*4 + t;
    if (n < kN){ P[(size_t)n*64 + j] = accP[t]; Q[(size_t)n*64 + j] = accQ[t]; }
  }
}

// ---------------- per-layer: edge MLP  e = relu(e + (relu(P[r]+Q[c]+e@W1c)@W2 + b2)) ----
__global__ __launch_bounds__(256) void k_mlp(
    const float* __restrict__ P, const float* __restrict__ Q,
    const float* __restrict__ W1c, const float* __restrict__ W2,
    const float* __restrict__ b2,
    const int* __restrict__ row, const int* __restrict__ col,
    float* __restrict__ e){
  __shared__ float ec_lds[4][64];
  __shared__ float h_lds[4][64];
  float w1[64], w2[64];
  int lane = threadIdx.x & 63, wave = threadIdx.x >> 6;
#pragma unroll
  for (int k = 0; k < 64; k++){ w1[k] = W1c[k*64 + lane]; w2[k] = W2[k*64 + lane]; }
  float b2v = b2[lane];
  int widx = blockIdx.x*4 + wave, nw = gridDim.x*4;
  for (int eid = widx; eid < kE; eid += nw){
    int r = row[eid], c = col[eid];
    float ec = e[(size_t)eid*64 + lane];
    float hp = P[(size_t)r*64 + lane] + Q[(size_t)c*64 + lane];
    ec_lds[wave][lane] = ec;
    float h0=0.f,h1=0.f,h2=0.f,h3=0.f;
    const float4* ep = (const float4*)&ec_lds[wave][0];
#pragma unroll
    for (int k4 = 0; k4 < 16; k4++){
      float4 v = ep[k4];
      h0 += v.x * w1[k4*4+0]; h1 += v.y * w1[k4*4+1];
      h2 += v.z * w1[k4*4+2]; h3 += v.w * w1[k4*4+3];
    }
    float h = fmaxf(hp + ((h0+h1)+(h2+h3)), 0.f);
    h_lds[wave][lane] = h;
    float o0=b2v,o1=0.f,o2=0.f,o3=0.f;
    const float4* hq = (const float4*)&h_lds[wave][0];
#pragma unroll
    for (int k4 = 0; k4 < 16; k4++){
      float4 v = hq[k4];
      o0 += v.x * w2[k4*4+0]; o1 += v.y * w2[k4*4+1];
      o2 += v.z * w2[k4*4+2]; o3 += v.w * w2[k4*4+3];
    }
    e[(size_t)eid*64 + lane] = fmaxf(ec + ((o0+o1)+(o2+o3)), 0.f);
  }
}

// ---------------- host ----------------
extern "C" void kernel_launch(void* const* d_in, const int* in_sizes, int n_in,
                              void* d_out, int out_size, void* d_ws, size_t ws_size,
                              hipStream_t stream) {
  const float* node_feat = (const float*)d_in[0];
  const int*   edge_idx  = (const int*)d_in[1];
  const float* edge_attr = (const float*)d_in[2];
  const float* W_node = (const float*)d_in[3];
  const float* b_node = (const float*)d_in[4];
  const float* W_edge = (const float*)d_in[5];
  const float* b_edge = (const float*)d_in[6];
  const float* Wl   = (const float*)d_in[7];
  const float* bl   = (const float*)d_in[8];
  const float* Wr   = (const float*)d_in[9];
  const float* br   = (const float*)d_in[10];
  const float* We   = (const float*)d_in[11];
  const float* att  = (const float*)d_in[12];
  const float* cvb  = (const float*)d_in[13];
  const float* lng  = (const float*)d_in[14];
  const float* lnb  = (const float*)d_in[15];
  const float* euW1 = (const float*)d_in[16];
  const float* eub1 = (const float*)d_in[17];
  const float* euW2 = (const float*)d_in[18];
  const float* eub2 = (const float*)d_in[19];

  const int* row = edge_idx;
  const int* col = edge_idx + kE;

  float* x = (float*)d_out;                      // N x 64
  float* e = (float*)d_out + (size_t)kN*kD;      // E x 64

  // carve workspace
  char* p = (char*)d_ws;
  auto carve = [&](size_t bytes)->void*{
    void* r = (void*)p;
    p += (bytes + 255) & ~(size_t)255;
    return r;
  };
  float* xl     = (float*)carve((size_t)kN*kHD*4);
  float* xr     = (float*)carve((size_t)kN*kHD*4);
  float* P      = (float*)carve((size_t)kN*kD*4);
  float* Q      = (float*)carve((size_t)kN*kD*4);
  int* deg      = (int*)carve((size_t)kN*4);
  int* col_start= (int*)carve((size_t)(kN+1)*4);
  int* fill     = (int*)carve((size_t)kN*4);
  int* edge_ids = (int*)carve((size_t)kE*4);

  // CSR build (graph is layer-invariant)
  hipMemsetAsync(deg, 0, (size_t)kN*4, stream);
  hipMemsetAsync(fill, 0, (size_t)kN*4, stream);
  k_deg<<<(kE+255)/256, 256, 0, stream>>>(col, deg);
  k_scan<<<1, 1024, 0, stream>>>(deg, col_start);
  k_fill<<<(kE+255)/256, 256, 0, stream>>>(col, col_start, fill, edge_ids);

  // initial embeddings
  k_x0<<<(kN*kD+255)/256, 256, 0, stream>>>(node_feat, W_node, b_node, x);
  k_e0<<<(kE*kD+255)/256, 256, 0, stream>>>(edge_attr, W_edge, b_edge, e);

  for (int i = 0; i < 3; i++){
    const float* Wl_i  = Wl  + (size_t)i*kD*kHD;
    const float* bl_i  = bl  + (size_t)i*kHD;
    const float* Wr_i  = Wr  + (size_t)i*kD*kHD;
    const float* br_i  = br  + (size_t)i*kHD;
    const float* We_i  = We  + (size_t)i*kD*kHD;
    const float* att_i = att + (size_t)i*kHD;
    const float* cvb_i = cvb + (size_t)i*kD;
    const float* lng_i = lng + (size_t)i*kD;
    const float* lnb_i = lnb + (size_t)i*kD;
    const float* W1_i  = euW1 + (size_t)i*192*64;
    const float* b1_i  = eub1 + (size_t)i*kD;
    const float* W2_i  = euW2 + (size_t)i*64*64;
    const float* b2_i  = eub2 + (size_t)i*kD;

    k_xlr<<<(kN + XLR_NPB - 1)/XLR_NPB, 256, 0, stream>>>(x, Wl_i, bl_i, Wr_i, br_i, xl, xr);
    k_gat_fused<<<2048, 256, 0, stream>>>(e, xl, xr, row, col_start, edge_ids,
                                          We_i, att_i, cvb_i, lng_i, lnb_i, x);
    k_pq<<<(kN + PQ_NPB - 1)/PQ_NPB, 256, 0, stream>>>(x, W1_i, b1_i, P, Q);
    k_mlp<<<2048, 256, 0, stream>>>(P, Q, W1_i + 128*64, W2_i, b2_i, row, col, e);
  }
}

// Round 3
// 1984.603 us; speedup vs baseline: 1.7222x; 1.7222x over previous
//
#include <hip/hip_runtime.h>
#include <hip/hip_bf16.h>
#include <cstdint>
#include <cstddef>

// Problem constants (fixed by the reference).
constexpr int kN  = 25000;
constexpr int kE  = 400000;
constexpr int kEN = kE + kN;
constexpr int kD  = 64;
constexpr int kH  = 4;
constexpr int kHD = 256;       // H * DH

typedef __attribute__((ext_vector_type(8))) short short8;
typedef __attribute__((ext_vector_type(4))) float f32x4;

__device__ __forceinline__ float lrelu02(float x){ return x > 0.f ? x : 0.2f*x; }
__device__ __forceinline__ unsigned short f2bf(float f){
  __hip_bfloat16 h = __float2bfloat16(f);
  return *reinterpret_cast<unsigned short*>(&h);
}

// ---------------- CSR build ----------------
__global__ void k_deg(const int* __restrict__ col, int* __restrict__ deg){
  int i = blockIdx.x*256 + threadIdx.x;
  if (i < kE) atomicAdd(&deg[col[i]], 1);
}

__global__ void k_scan(const int* __restrict__ deg, int* __restrict__ col_start){
  __shared__ int lds[1024];
  __shared__ int carry_s;
  int t = threadIdx.x;
  if (t == 0) carry_s = 0;
  __syncthreads();
  for (int base = 0; base < kN; base += 1024){
    int v = (base + t < kN) ? deg[base + t] : 0;
    lds[t] = v; __syncthreads();
    for (int off = 1; off < 1024; off <<= 1){
      int add = (t >= off) ? lds[t - off] : 0;
      __syncthreads();
      lds[t] += add;
      __syncthreads();
    }
    int incl = lds[t];
    int carry = carry_s;
    if (base + t < kN) col_start[base + t] = carry + incl - v;
    __syncthreads();
    if (t == 0) carry_s = carry + lds[1023];
    __syncthreads();
  }
  if (t == 0) col_start[kN] = carry_s;
}

__global__ void k_fill(const int* __restrict__ col, const int* __restrict__ col_start,
                       int* __restrict__ fill, int* __restrict__ edge_ids){
  int i = blockIdx.x*256 + threadIdx.x;
  if (i < kE){
    int c = col[i];
    int p = atomicAdd(&fill[c], 1);
    edge_ids[col_start[c] + p] = i;
  }
}

// ---------------- weight prepack: WeT[l][j][k] = bf16(We[l][k][j]) ----------------
__global__ void k_prep(const float* __restrict__ We, unsigned short* __restrict__ WeT){
  int idx = blockIdx.x*256 + threadIdx.x;      // l*16384 + j*64 + k
  if (idx >= 3*256*64) return;
  int l = idx >> 14, j = (idx >> 6) & 255, k = idx & 63;
  WeT[idx] = f2bf(We[(size_t)l*16384 + k*256 + j]);
}

// ---------------- initial embeddings ----------------
__global__ void k_x0(const float* __restrict__ nf, const float* __restrict__ W,
                     const float* __restrict__ b, float* __restrict__ x){
  int i = blockIdx.x*256 + threadIdx.x;
  if (i >= kN*kD) return;
  int n = i >> 6, d = i & 63;
  float acc = b[d];
#pragma unroll
  for (int k = 0; k < 16; k++) acc += nf[n*16 + k] * W[k*64 + d];
  x[i] = fmaxf(acc, 0.f);
}

__global__ void k_e0(const float* __restrict__ ea, const float* __restrict__ W,
                     const float* __restrict__ b, float* __restrict__ e,
                     unsigned short* __restrict__ ebf){
  long long i = (long long)blockIdx.x*256 + threadIdx.x;
  if (i >= (long long)kE*kD) return;
  int n = (int)(i >> 6), d = (int)(i & 63);
  float acc = b[d];
#pragma unroll
  for (int k = 0; k < 4; k++) acc += ea[n*4 + k] * W[k*64 + d];
  float v = fmaxf(acc, 0.f);
  e[i] = v; ebf[i] = f2bf(v);
}

// ---------------- per-layer: xl = x@Wl+bl, xr = x@Wr+br  (N x 256 each) ----------------
#define XLR_NPB 8
__global__ __launch_bounds__(256) void k_xlr(const float* __restrict__ x,
    const float* __restrict__ Wl, const float* __restrict__ bl,
    const float* __restrict__ Wr, const float* __restrict__ br,
    float* __restrict__ xl, float* __restrict__ xr){
  __shared__ float xs[XLR_NPB*64];
  int j = threadIdx.x;
  int n0 = blockIdx.x * XLR_NPB;
  for (int i = j; i < XLR_NPB*64; i += 256){
    int n = n0 + (i >> 6);
    xs[i] = (n < kN) ? x[(size_t)n*64 + (i & 63)] : 0.f;
  }
  __syncthreads();
  float accl[XLR_NPB], accr[XLR_NPB];
  float blv = bl[j], brv = br[j];
#pragma unroll
  for (int t = 0; t < XLR_NPB; t++){ accl[t] = blv; accr[t] = brv; }
  for (int k = 0; k < 64; k++){
    float wl = Wl[k*kHD + j], wr = Wr[k*kHD + j];
#pragma unroll
    for (int t = 0; t < XLR_NPB; t++){
      float xv = xs[t*64 + k];
      accl[t] += xv * wl; accr[t] += xv * wr;
    }
  }
#pragma unroll
  for (int t = 0; t < XLR_NPB; t++){
    int n = n0 + t;
    if (n < kN){ xl[(size_t)n*kHD + j] = accl[t]; xr[(size_t)n*kHD + j] = accr[t]; }
  }
}

// ---------------- per-layer: e_loop (bf16) = mean of incoming e rows ----------------
__global__ __launch_bounds__(256) void k_eloop(const float* __restrict__ e,
    const int* __restrict__ col_start, const int* __restrict__ edge_ids,
    unsigned short* __restrict__ eloop_bf){
  int wave = threadIdx.x >> 6, lane = threadIdx.x & 63;
  int n = blockIdx.x*4 + wave;
  if (n >= kN) return;
  int s0 = col_start[n], s1 = col_start[n+1];
  float acc = 0.f;
  for (int p = s0; p < s1; p++){
    int eid = edge_ids[p];
    acc += e[(size_t)eid*64 + lane];
  }
  int dg = s1 - s0;
  eloop_bf[(size_t)n*64 + lane] = f2bf(acc / (float)(dg > 0 ? dg : 1));
}

// ---------------- per-layer: MFMA score kernel ----------------
// Wave processes a 16-edge tile: C[d][edge] = WeT_tile(16x64) @ e_tile^T(64x16)
// via 2 chained mfma_f32_16x16x32_bf16 per M-tile; then per-lane float4 gathers
// of xl/xr at its C rows, lrelu*att, and a 2-step shfl_xor reduce over k-groups.
__global__ __launch_bounds__(256) void k_score_mfma(
    const unsigned short* __restrict__ e_bf,     // [E][64]
    const unsigned short* __restrict__ eloop_bf, // [N][64]
    const float* __restrict__ xl, const float* __restrict__ xr,
    const int* __restrict__ row, const int* __restrict__ col,
    const unsigned short* __restrict__ WeT,      // [256][64] bf16
    const float* __restrict__ att,               // [4][64]
    float* __restrict__ score)                   // [EN][4]
{
  int lane = threadIdx.x & 63;
  int wid  = (blockIdx.x*256 + threadIdx.x) >> 6;
  int nw   = (gridDim.x*256) >> 6;
  int e16  = lane & 15;          // edge-in-tile (B col / C col / A row)
  int kb   = lane >> 4;          // k-block (A/B), row-group (C)

  constexpr int NT = (kEN + 15)/16;
  for (int tile = wid; tile < NT; tile += nw){
    int eid = tile*16 + e16;
    int eidc = (eid < kEN) ? eid : 0;
    const unsigned short* erow = (eidc < kE) ? (e_bf + (size_t)eidc*64)
                                             : (eloop_bf + (size_t)(eidc - kE)*64);
    short8 b0 = *(const short8*)(erow + kb*8);
    short8 b1 = *(const short8*)(erow + 32 + kb*8);
    int r = (eidc < kE) ? row[eidc] : (eidc - kE);
    int c = (eidc < kE) ? col[eidc] : (eidc - kE);
    const float* xlr_ = xl + (size_t)r*kHD;
    const float* xrc_ = xr + (size_t)c*kHD;

#pragma unroll
    for (int h = 0; h < 4; h++){
      float sc = 0.f;
#pragma unroll
      for (int mt = 0; mt < 4; mt++){
        const unsigned short* arow = WeT + (size_t)(h*64 + mt*16 + e16)*64 + kb*8;
        short8 a0 = *(const short8*)(arow);
        short8 a1 = *(const short8*)(arow + 32);
        f32x4 acc = {0.f,0.f,0.f,0.f};
        acc = __builtin_amdgcn_mfma_f32_16x16x32_bf16(a0, b0, acc, 0, 0, 0);
        acc = __builtin_amdgcn_mfma_f32_16x16x32_bf16(a1, b1, acc, 0, 0, 0);
        int dbase = h*64 + mt*16 + kb*4;     // this lane's 4 C rows
        f32x4 xlv = *(const f32x4*)(xlr_ + dbase);
        f32x4 xrv = *(const f32x4*)(xrc_ + dbase);
        f32x4 atv = *(const f32x4*)(att + dbase);
#pragma unroll
        for (int q = 0; q < 4; q++){
          float msg = acc[q] + xlv[q] + xrv[q];
          sc += lrelu02(msg) * atv[q];
        }
      }
      sc += __shfl_xor(sc, 16);
      sc += __shfl_xor(sc, 32);
      int weid = tile*16 + lane;
      if (lane < 16 && weid < kEN) score[(size_t)weid*kH + h] = sc;
    }
  }
}

// ---------------- per-layer: segment max & expsum (incl self-loop) ----------------
__global__ void k_segmax(const float* __restrict__ score,
    const int* __restrict__ col_start, const int* __restrict__ edge_ids,
    float* __restrict__ mmax, float* __restrict__ ssum){
  int i = blockIdx.x*256 + threadIdx.x;
  if (i >= kN*kH) return;
  int n = i >> 2, h = i & 3;
  float selfsc = score[(size_t)(kE + n)*kH + h];
  float m = selfsc;
  int s0 = col_start[n], s1 = col_start[n+1];
  for (int p = s0; p < s1; p++)
    m = fmaxf(m, score[(size_t)edge_ids[p]*kH + h]);
  float s = expf(selfsc - m);
  for (int p = s0; p < s1; p++)
    s += expf(score[(size_t)edge_ids[p]*kH + h] - m);
  mmax[i] = m; ssum[i] = s;
}

// ---------------- per-layer: aggregate + head-mean + residual + LN + relu ----------------
__global__ __launch_bounds__(256) void k_agg_ln(
    const float* __restrict__ xl, const float* __restrict__ score,
    const int* __restrict__ row,
    const int* __restrict__ col_start, const int* __restrict__ edge_ids,
    const float* __restrict__ mmax, const float* __restrict__ ssum,
    const float* __restrict__ conv_b, const float* __restrict__ ln_g,
    const float* __restrict__ ln_b, float* __restrict__ x){
  int n = blockIdx.x;
  int j = threadIdx.x, h = j >> 6, d = j & 63;
  float m = mmax[n*4 + h];
  float inv = 1.f / ssum[n*4 + h];
  float a = expf(score[(size_t)(kE + n)*kH + h] - m) * inv;
  float acc = a * xl[(size_t)n*kHD + j];
  int s0 = col_start[n], s1 = col_start[n+1];
  for (int p = s0; p < s1; p++){
    int eid = edge_ids[p];
    int r = row[eid];
    float ae = expf(score[(size_t)eid*kH + h] - m) * inv;
    acc += ae * xl[(size_t)r*kHD + j];
  }
  __shared__ float lds[256];
  lds[j] = acc; __syncthreads();
  if (j < 64){
    float upd = (lds[d] + lds[64+d] + lds[128+d] + lds[192+d]) * 0.25f + conv_b[d];
    float y = x[(size_t)n*64 + d] + upd;
    float mu = y;
#pragma unroll
    for (int off = 32; off; off >>= 1) mu += __shfl_xor(mu, off);
    mu *= (1.f/64.f);
    float diff = y - mu;
    float var = diff * diff;
#pragma unroll
    for (int off = 32; off; off >>= 1) var += __shfl_xor(var, off);
    var *= (1.f/64.f);
    float out = diff * rsqrtf(var + 1e-5f) * ln_g[d] + ln_b[d];
    x[(size_t)n*64 + d] = fmaxf(out, 0.f);
  }
}

// ---------------- per-layer: P = x@W1a + b1, Q = x@W1b ----------------
#define PQ_NPB 16
__global__ __launch_bounds__(256) void k_pq(const float* __restrict__ x,
    const float* __restrict__ W1, const float* __restrict__ b1,
    float* __restrict__ P, float* __restrict__ Q){
  __shared__ float xs[PQ_NPB*64];
  int tid = threadIdx.x;
  int j = tid & 63;
  int s = tid >> 6;
  int n0 = blockIdx.x * PQ_NPB;
  for (int i = tid; i < PQ_NPB*64; i += 256){
    int n = n0 + (i >> 6);
    xs[i] = (n < kN) ? x[(size_t)n*64 + (i & 63)] : 0.f;
  }
  __syncthreads();
  float accP[4], accQ[4];
  float b1v = b1[j];
#pragma unroll
  for (int t = 0; t < 4; t++){ accP[t] = b1v; accQ[t] = 0.f; }
  for (int k = 0; k < 64; k++){
    float wa = W1[k*64 + j];
    float wb = W1[(64 + k)*64 + j];
#pragma unroll
    for (int t = 0; t < 4; t++){
      float xv = xs[(s*4 + t)*64 + k];
      accP[t] += xv * wa; accQ[t] += xv * wb;
    }
  }
#pragma unroll
  for (int t = 0; t < 4; t++){
    int n = n0 + s*4 + t;
    if (n < kN){ P[(size_t)n*64 + j] = accP[t]; Q[(size_t)n*64 + j] = accQ[t]; }
  }
}

// ---------------- per-layer: edge MLP ----------------
__global__ __launch_bounds__(256) void k_mlp(
    const float* __restrict__ P, const float* __restrict__ Q,
    const float* __restrict__ W1c, const float* __restrict__ W2,
    const float* __restrict__ b2,
    const int* __restrict__ row, const int* __restrict__ col,
    float* __restrict__ e, unsigned short* __restrict__ ebf){
  __shared__ float ec_lds[4][64];
  __shared__ float h_lds[4][64];
  float w1[64], w2[64];
  int lane = threadIdx.x & 63, wave = threadIdx.x >> 6;
#pragma unroll
  for (int k = 0; k < 64; k++){ w1[k] = W1c[k*64 + lane]; w2[k] = W2[k*64 + lane]; }
  float b2v = b2[lane];
  int widx = blockIdx.x*4 + wave, nw = gridDim.x*4;
  for (int eid = widx; eid < kE; eid += nw){
    int r = row[eid], c = col[eid];
    float ec = e[(size_t)eid*64 + lane];
    float hp = P[(size_t)r*64 + lane] + Q[(size_t)c*64 + lane];
    ec_lds[wave][lane] = ec;
    float h0=0.f,h1=0.f,h2=0.f,h3=0.f;
    const float4* ep = (const float4*)&ec_lds[wave][0];
#pragma unroll
    for (int k4 = 0; k4 < 16; k4++){
      float4 v = ep[k4];
      h0 += v.x * w1[k4*4+0]; h1 += v.y * w1[k4*4+1];
      h2 += v.z * w1[k4*4+2]; h3 += v.w * w1[k4*4+3];
    }
    float h = fmaxf(hp + ((h0+h1)+(h2+h3)), 0.f);
    h_lds[wave][lane] = h;
    float o0=b2v,o1=0.f,o2=0.f,o3=0.f;
    const float4* hq = (const float4*)&h_lds[wave][0];
#pragma unroll
    for (int k4 = 0; k4 < 16; k4++){
      float4 v = hq[k4];
      o0 += v.x * w2[k4*4+0]; o1 += v.y * w2[k4*4+1];
      o2 += v.z * w2[k4*4+2]; o3 += v.w * w2[k4*4+3];
    }
    float ne = fmaxf(ec + ((o0+o1)+(o2+o3)), 0.f);
    e[(size_t)eid*64 + lane] = ne;
    ebf[(size_t)eid*64 + lane] = f2bf(ne);
  }
}

// ---------------- host ----------------
extern "C" void kernel_launch(void* const* d_in, const int* in_sizes, int n_in,
                              void* d_out, int out_size, void* d_ws, size_t ws_size,
                              hipStream_t stream) {
  const float* node_feat = (const float*)d_in[0];
  const int*   edge_idx  = (const int*)d_in[1];
  const float* edge_attr = (const float*)d_in[2];
  const float* W_node = (const float*)d_in[3];
  const float* b_node = (const float*)d_in[4];
  const float* W_edge = (const float*)d_in[5];
  const float* b_edge = (const float*)d_in[6];
  const float* Wl   = (const float*)d_in[7];
  const float* bl   = (const float*)d_in[8];
  const float* Wr   = (const float*)d_in[9];
  const float* br   = (const float*)d_in[10];
  const float* We   = (const float*)d_in[11];
  const float* att  = (const float*)d_in[12];
  const float* cvb  = (const float*)d_in[13];
  const float* lng  = (const float*)d_in[14];
  const float* lnb  = (const float*)d_in[15];
  const float* euW1 = (const float*)d_in[16];
  const float* eub1 = (const float*)d_in[17];
  const float* euW2 = (const float*)d_in[18];
  const float* eub2 = (const float*)d_in[19];

  const int* row = edge_idx;
  const int* col = edge_idx + kE;

  float* x = (float*)d_out;                      // N x 64
  float* e = (float*)d_out + (size_t)kN*kD;      // E x 64

  char* p = (char*)d_ws;
  auto carve = [&](size_t bytes)->void*{
    void* r = (void*)p;
    p += (bytes + 255) & ~(size_t)255;
    return r;
  };
  float* xl     = (float*)carve((size_t)kN*kHD*4);
  float* xr     = (float*)carve((size_t)kN*kHD*4);
  float* P      = (float*)carve((size_t)kN*kD*4);
  float* Q      = (float*)carve((size_t)kN*kD*4);
  unsigned short* e_bf     = (unsigned short*)carve((size_t)kE*kD*2);
  unsigned short* eloop_bf = (unsigned short*)carve((size_t)kN*kD*2);
  unsigned short* WeT      = (unsigned short*)carve((size_t)3*kHD*kD*2);
  float* score  = (float*)carve((size_t)kEN*kH*4);
  float* mmax   = (float*)carve((size_t)kN*kH*4);
  float* ssum   = (float*)carve((size_t)kN*kH*4);
  int* deg      = (int*)carve((size_t)kN*4);
  int* col_start= (int*)carve((size_t)(kN+1)*4);
  int* fill     = (int*)carve((size_t)kN*4);
  int* edge_ids = (int*)carve((size_t)kE*4);

  // CSR build (graph is layer-invariant)
  hipMemsetAsync(deg, 0, (size_t)kN*4, stream);
  hipMemsetAsync(fill, 0, (size_t)kN*4, stream);
  k_deg<<<(kE+255)/256, 256, 0, stream>>>(col, deg);
  k_scan<<<1, 1024, 0, stream>>>(deg, col_start);
  k_fill<<<(kE+255)/256, 256, 0, stream>>>(col, col_start, fill, edge_ids);

  // weight prepack + initial embeddings
  k_prep<<<192, 256, 0, stream>>>(We, WeT);
  k_x0<<<(kN*kD+255)/256, 256, 0, stream>>>(node_feat, W_node, b_node, x);
  k_e0<<<(kE*kD+255)/256, 256, 0, stream>>>(edge_attr, W_edge, b_edge, e, e_bf);

  for (int i = 0; i < 3; i++){
    const float* Wl_i  = Wl  + (size_t)i*kD*kHD;
    const float* bl_i  = bl  + (size_t)i*kHD;
    const float* Wr_i  = Wr  + (size_t)i*kD*kHD;
    const float* br_i  = br  + (size_t)i*kHD;
    const float* att_i = att + (size_t)i*kHD;
    const float* cvb_i = cvb + (size_t)i*kD;
    const float* lng_i = lng + (size_t)i*kD;
    const float* lnb_i = lnb + (size_t)i*kD;
    const float* W1_i  = euW1 + (size_t)i*192*64;
    const float* b1_i  = eub1 + (size_t)i*kD;
    const float* W2_i  = euW2 + (size_t)i*64*64;
    const float* b2_i  = eub2 + (size_t)i*kD;
    const unsigned short* WeT_i = WeT + (size_t)i*kHD*kD;

    k_xlr<<<(kN + XLR_NPB - 1)/XLR_NPB, 256, 0, stream>>>(x, Wl_i, bl_i, Wr_i, br_i, xl, xr);
    k_eloop<<<(kN + 3)/4, 256, 0, stream>>>(e, col_start, edge_ids, eloop_bf);
    k_score_mfma<<<2048, 256, 0, stream>>>(e_bf, eloop_bf, xl, xr, row, col,
                                           WeT_i, att_i, score);
    k_segmax<<<(kN*kH + 255)/256, 256, 0, stream>>>(score, col_start, edge_ids, mmax, ssum);
    k_agg_ln<<<kN, 256, 0, stream>>>(xl, score, row, col_start, edge_ids, mmax, ssum,
                                     cvb_i, lng_i, lnb_i, x);
    k_pq<<<(kN + PQ_NPB - 1)/PQ_NPB, 256, 0, stream>>>(x, W1_i, b1_i, P, Q);
    k_mlp<<<2048, 256, 0, stream>>>(P, Q, W1_i + 128*64, W2_i, b2_i, row, col, e, e_bf);
  }
}

// Round 4
// 1596.236 us; speedup vs baseline: 2.1412x; 1.2433x over previous
//
#include <hip/hip_runtime.h>
#include <hip/hip_bf16.h>
#include <cstdint>
#include <cstddef>

// Problem constants (fixed by the reference).
constexpr int kN  = 25000;
constexpr int kE  = 400000;
constexpr int kEN = kE + kN;
constexpr int kD  = 64;
constexpr int kH  = 4;
constexpr int kHD = 256;       // H * DH

typedef __attribute__((ext_vector_type(8))) short short8;
typedef __attribute__((ext_vector_type(4))) float f32x4;

__device__ __forceinline__ float lrelu02(float x){ return x > 0.f ? x : 0.2f*x; }
__device__ __forceinline__ unsigned short f2bf(float f){
  __hip_bfloat16 h = __float2bfloat16(f);
  return *reinterpret_cast<unsigned short*>(&h);
}
__device__ __forceinline__ float bf2f(unsigned short u){
  return __uint_as_float(((unsigned)u) << 16);
}
__device__ __forceinline__ float bf_lo(unsigned u){ return __uint_as_float(u << 16); }
__device__ __forceinline__ float bf_hi(unsigned u){ return __uint_as_float(u & 0xffff0000u); }
__device__ __forceinline__ unsigned pack_bf2(float a, float b){
  return ((unsigned)f2bf(a)) | (((unsigned)f2bf(b)) << 16);
}

// ---------------- CSR build ----------------
__global__ void k_deg(const int* __restrict__ col, int* __restrict__ deg){
  int i = blockIdx.x*256 + threadIdx.x;
  if (i < kE) atomicAdd(&deg[col[i]], 1);
}

__global__ void k_scan(const int* __restrict__ deg, int* __restrict__ col_start){
  __shared__ int lds[1024];
  __shared__ int carry_s;
  int t = threadIdx.x;
  if (t == 0) carry_s = 0;
  __syncthreads();
  for (int base = 0; base < kN; base += 1024){
    int v = (base + t < kN) ? deg[base + t] : 0;
    lds[t] = v; __syncthreads();
    for (int off = 1; off < 1024; off <<= 1){
      int add = (t >= off) ? lds[t - off] : 0;
      __syncthreads();
      lds[t] += add;
      __syncthreads();
    }
    int incl = lds[t];
    int carry = carry_s;
    if (base + t < kN) col_start[base + t] = carry + incl - v;
    __syncthreads();
    if (t == 0) carry_s = carry + lds[1023];
    __syncthreads();
  }
  if (t == 0) col_start[kN] = carry_s;
}

__global__ void k_fill(const int* __restrict__ col, const int* __restrict__ col_start,
                       int* __restrict__ fill, int* __restrict__ edge_ids){
  int i = blockIdx.x*256 + threadIdx.x;
  if (i < kE){
    int c = col[i];
    int p = atomicAdd(&fill[c], 1);
    edge_ids[col_start[c] + p] = i;
  }
}

// ---------------- weight prepack ----------------
// WeT[l][j][k] = bf16(We[l][k][j])   (j in [0,256), k in [0,64))
__global__ void k_prep(const float* __restrict__ We, unsigned short* __restrict__ WeT){
  int idx = blockIdx.x*256 + threadIdx.x;
  if (idx >= 3*256*64) return;
  int l = idx >> 14, j = (idx >> 6) & 255, k = idx & 63;
  WeT[idx] = f2bf(We[(size_t)l*16384 + k*256 + j]);
}

// W1cT[l][d][k] = bf16(euW1[l][128+k][d]);  W2T[l][d][k] = bf16(euW2[l][k][d])
__global__ void k_prep2(const float* __restrict__ euW1, const float* __restrict__ euW2,
                        unsigned short* __restrict__ W1cT, unsigned short* __restrict__ W2T){
  int idx = blockIdx.x*256 + threadIdx.x;
  if (idx >= 3*64*64) return;
  int l = idx >> 12, rem = idx & 4095, d = rem >> 6, k = rem & 63;
  W1cT[idx] = f2bf(euW1[(size_t)l*192*64 + (size_t)(128+k)*64 + d]);
  W2T[idx]  = f2bf(euW2[(size_t)l*64*64  + (size_t)k*64 + d]);
}

// ---------------- initial embeddings ----------------
__global__ void k_x0(const float* __restrict__ nf, const float* __restrict__ W,
                     const float* __restrict__ b, float* __restrict__ x){
  int i = blockIdx.x*256 + threadIdx.x;
  if (i >= kN*kD) return;
  int n = i >> 6, d = i & 63;
  float acc = b[d];
#pragma unroll
  for (int k = 0; k < 16; k++) acc += nf[n*16 + k] * W[k*64 + d];
  x[i] = fmaxf(acc, 0.f);
}

__global__ void k_e0(const float* __restrict__ ea, const float* __restrict__ W,
                     const float* __restrict__ b, float* __restrict__ e,
                     unsigned short* __restrict__ ebf){
  long long i = (long long)blockIdx.x*256 + threadIdx.x;
  if (i >= (long long)kE*kD) return;
  int n = (int)(i >> 6), d = (int)(i & 63);
  float acc = b[d];
#pragma unroll
  for (int k = 0; k < 4; k++) acc += ea[n*4 + k] * W[k*64 + d];
  float v = fmaxf(acc, 0.f);
  e[i] = v; ebf[i] = f2bf(v);
}

// ---------------- per-layer: xl_bf = bf16(x@Wl+bl), xr_bf = bf16(x@Wr+br) ----------------
#define XLR_NPB 8
__global__ __launch_bounds__(256) void k_xlr(const float* __restrict__ x,
    const float* __restrict__ Wl, const float* __restrict__ bl,
    const float* __restrict__ Wr, const float* __restrict__ br,
    unsigned short* __restrict__ xl_bf, unsigned short* __restrict__ xr_bf){
  __shared__ float xs[XLR_NPB*64];
  int j = threadIdx.x;
  int n0 = blockIdx.x * XLR_NPB;
  for (int i = j; i < XLR_NPB*64; i += 256){
    int n = n0 + (i >> 6);
    xs[i] = (n < kN) ? x[(size_t)n*64 + (i & 63)] : 0.f;
  }
  __syncthreads();
  float accl[XLR_NPB], accr[XLR_NPB];
  float blv = bl[j], brv = br[j];
#pragma unroll
  for (int t = 0; t < XLR_NPB; t++){ accl[t] = blv; accr[t] = brv; }
  for (int k = 0; k < 64; k++){
    float wl = Wl[k*kHD + j], wr = Wr[k*kHD + j];
#pragma unroll
    for (int t = 0; t < XLR_NPB; t++){
      float xv = xs[t*64 + k];
      accl[t] += xv * wl; accr[t] += xv * wr;
    }
  }
#pragma unroll
  for (int t = 0; t < XLR_NPB; t++){
    int n = n0 + t;
    if (n < kN){
      xl_bf[(size_t)n*kHD + j] = f2bf(accl[t]);
      xr_bf[(size_t)n*kHD + j] = f2bf(accr[t]);
    }
  }
}

// ---------------- per-layer: e_loop (bf16) = mean of incoming e rows (reads bf16 e) ----
__global__ __launch_bounds__(256) void k_eloop(const unsigned short* __restrict__ ebf,
    const int* __restrict__ col_start, const int* __restrict__ edge_ids,
    unsigned short* __restrict__ eloop_bf){
  int wave = threadIdx.x >> 6, lane = threadIdx.x & 63;
  int n = blockIdx.x*4 + wave;
  if (n >= kN) return;
  int s0 = col_start[n], s1 = col_start[n+1];
  float acc = 0.f;
  for (int p = s0; p < s1; p++){
    int eid = edge_ids[p];
    acc += bf2f(ebf[(size_t)eid*64 + lane]);
  }
  int dg = s1 - s0;
  eloop_bf[(size_t)n*64 + lane] = f2bf(acc / (float)(dg > 0 ? dg : 1));
}

// ---------------- per-layer: MFMA score kernel (bf16 xl/xr gathers) ----------------
__global__ __launch_bounds__(256) void k_score_mfma(
    const unsigned short* __restrict__ e_bf,     // [E][64]
    const unsigned short* __restrict__ eloop_bf, // [N][64]
    const unsigned short* __restrict__ xl_bf,    // [N][256]
    const unsigned short* __restrict__ xr_bf,    // [N][256]
    const int* __restrict__ row, const int* __restrict__ col,
    const unsigned short* __restrict__ WeT,      // [256][64] bf16
    const float* __restrict__ att,               // [4][64]
    float* __restrict__ score)                   // [EN][4]
{
  int lane = threadIdx.x & 63;
  int wid  = (blockIdx.x*256 + threadIdx.x) >> 6;
  int nw   = (gridDim.x*256) >> 6;
  int e16  = lane & 15;          // edge-in-tile (B col / C col / A row)
  int kb   = lane >> 4;          // k-block (A/B), row-group (C)

  constexpr int NT = (kEN + 15)/16;
  for (int tile = wid; tile < NT; tile += nw){
    int eid = tile*16 + e16;
    int eidc = (eid < kEN) ? eid : 0;
    const unsigned short* erow = (eidc < kE) ? (e_bf + (size_t)eidc*64)
                                             : (eloop_bf + (size_t)(eidc - kE)*64);
    short8 b0 = *(const short8*)(erow + kb*8);
    short8 b1 = *(const short8*)(erow + 32 + kb*8);
    int r = (eidc < kE) ? row[eidc] : (eidc - kE);
    int c = (eidc < kE) ? col[eidc] : (eidc - kE);
    const unsigned short* xlr_ = xl_bf + (size_t)r*kHD;
    const unsigned short* xrc_ = xr_bf + (size_t)c*kHD;

#pragma unroll
    for (int h = 0; h < 4; h++){
      float sc = 0.f;
#pragma unroll
      for (int mt = 0; mt < 4; mt++){
        const unsigned short* arow = WeT + (size_t)(h*64 + mt*16 + e16)*64 + kb*8;
        short8 a0 = *(const short8*)(arow);
        short8 a1 = *(const short8*)(arow + 32);
        f32x4 acc = {0.f,0.f,0.f,0.f};
        acc = __builtin_amdgcn_mfma_f32_16x16x32_bf16(a0, b0, acc, 0, 0, 0);
        acc = __builtin_amdgcn_mfma_f32_16x16x32_bf16(a1, b1, acc, 0, 0, 0);
        int dbase = h*64 + mt*16 + kb*4;     // this lane's 4 C rows
        uint2 xlu = *(const uint2*)(xlr_ + dbase);
        uint2 xru = *(const uint2*)(xrc_ + dbase);
        f32x4 atv = *(const f32x4*)(att + dbase);
        float xl0 = bf_lo(xlu.x), xl1 = bf_hi(xlu.x), xl2 = bf_lo(xlu.y), xl3 = bf_hi(xlu.y);
        float xr0 = bf_lo(xru.x), xr1 = bf_hi(xru.x), xr2 = bf_lo(xru.y), xr3 = bf_hi(xru.y);
        sc += lrelu02(acc[0] + xl0 + xr0) * atv[0];
        sc += lrelu02(acc[1] + xl1 + xr1) * atv[1];
        sc += lrelu02(acc[2] + xl2 + xr2) * atv[2];
        sc += lrelu02(acc[3] + xl3 + xr3) * atv[3];
      }
      sc += __shfl_xor(sc, 16);
      sc += __shfl_xor(sc, 32);
      int weid = tile*16 + lane;
      if (lane < 16 && weid < kEN) score[(size_t)weid*kH + h] = sc;
    }
  }
}

// ---------------- per-layer: segment max & expsum (incl self-loop) ----------------
__global__ void k_segmax(const float* __restrict__ score,
    const int* __restrict__ col_start, const int* __restrict__ edge_ids,
    float* __restrict__ mmax, float* __restrict__ ssum){
  int i = blockIdx.x*256 + threadIdx.x;
  if (i >= kN*kH) return;
  int n = i >> 2, h = i & 3;
  float selfsc = score[(size_t)(kE + n)*kH + h];
  float m = selfsc;
  int s0 = col_start[n], s1 = col_start[n+1];
  for (int p = s0; p < s1; p++)
    m = fmaxf(m, score[(size_t)edge_ids[p]*kH + h]);
  float s = expf(selfsc - m);
  for (int p = s0; p < s1; p++)
    s += expf(score[(size_t)edge_ids[p]*kH + h] - m);
  mmax[i] = m; ssum[i] = s;
}

// ---------------- per-layer: aggregate + head-mean + residual + LN + relu ----------------
__global__ __launch_bounds__(256) void k_agg_ln(
    const unsigned short* __restrict__ xl_bf, const float* __restrict__ score,
    const int* __restrict__ row,
    const int* __restrict__ col_start, const int* __restrict__ edge_ids,
    const float* __restrict__ mmax, const float* __restrict__ ssum,
    const float* __restrict__ conv_b, const float* __restrict__ ln_g,
    const float* __restrict__ ln_b, float* __restrict__ x){
  int n = blockIdx.x;
  int j = threadIdx.x, h = j >> 6, d = j & 63;
  float m = mmax[n*4 + h];
  float inv = 1.f / ssum[n*4 + h];
  float a = expf(score[(size_t)(kE + n)*kH + h] - m) * inv;
  float acc = a * bf2f(xl_bf[(size_t)n*kHD + j]);
  int s0 = col_start[n], s1 = col_start[n+1];
  for (int p = s0; p < s1; p++){
    int eid = edge_ids[p];
    int r = row[eid];
    float ae = expf(score[(size_t)eid*kH + h] - m) * inv;
    acc += ae * bf2f(xl_bf[(size_t)r*kHD + j]);
  }
  __shared__ float lds[256];
  lds[j] = acc; __syncthreads();
  if (j < 64){
    float upd = (lds[d] + lds[64+d] + lds[128+d] + lds[192+d]) * 0.25f + conv_b[d];
    float y = x[(size_t)n*64 + d] + upd;
    float mu = y;
#pragma unroll
    for (int off = 32; off; off >>= 1) mu += __shfl_xor(mu, off);
    mu *= (1.f/64.f);
    float diff = y - mu;
    float var = diff * diff;
#pragma unroll
    for (int off = 32; off; off >>= 1) var += __shfl_xor(var, off);
    var *= (1.f/64.f);
    float out = diff * rsqrtf(var + 1e-5f) * ln_g[d] + ln_b[d];
    x[(size_t)n*64 + d] = fmaxf(out, 0.f);
  }
}

// ---------------- per-layer: P = x@W1a + b1, Q = x@W1b ----------------
#define PQ_NPB 16
__global__ __launch_bounds__(256) void k_pq(const float* __restrict__ x,
    const float* __restrict__ W1, const float* __restrict__ b1,
    float* __restrict__ P, float* __restrict__ Q){
  __shared__ float xs[PQ_NPB*64];
  int tid = threadIdx.x;
  int j = tid & 63;
  int s = tid >> 6;
  int n0 = blockIdx.x * PQ_NPB;
  for (int i = tid; i < PQ_NPB*64; i += 256){
    int n = n0 + (i >> 6);
    xs[i] = (n < kN) ? x[(size_t)n*64 + (i & 63)] : 0.f;
  }
  __syncthreads();
  float accP[4], accQ[4];
  float b1v = b1[j];
#pragma unroll
  for (int t = 0; t < 4; t++){ accP[t] = b1v; accQ[t] = 0.f; }
  for (int k = 0; k < 64; k++){
    float wa = W1[k*64 + j];
    float wb = W1[(64 + k)*64 + j];
#pragma unroll
    for (int t = 0; t < 4; t++){
      float xv = xs[(s*4 + t)*64 + k];
      accP[t] += xv * wa; accQ[t] += xv * wb;
    }
  }
#pragma unroll
  for (int t = 0; t < 4; t++){
    int n = n0 + s*4 + t;
    if (n < kN){ P[(size_t)n*64 + j] = accP[t]; Q[(size_t)n*64 + j] = accQ[t]; }
  }
}

// ---------------- per-layer: edge MLP via MFMA ----------------
// Wave owns a 16-edge tile. H[d][edge] = relu(W1cT@e^T + P[r]+Q[c]) via 8 MFMAs,
// LDS round-trip (XOR-swizzled, wave-local) to re-fragment C->B, then
// O[d][edge] = W2T@H via 8 MFMAs; epilogue adds b2 + residual, relu, stores e+ebf.
__global__ __launch_bounds__(256) void k_mlp_mfma(
    float* __restrict__ e, unsigned short* __restrict__ ebf,
    const float* __restrict__ P, const float* __restrict__ Q,
    const unsigned short* __restrict__ W1cT,  // [64 d][64 k] bf16
    const unsigned short* __restrict__ W2T,   // [64 d][64 k] bf16
    const float* __restrict__ b2,
    const int* __restrict__ row, const int* __restrict__ col)
{
  __shared__ unsigned short Hl[4][1024];      // 2KB per wave
  int lane = threadIdx.x & 63, wv = threadIdx.x >> 6;
  int e16 = lane & 15, g = lane >> 4;
  int swz = (e16 & 7) << 4;
  char* Hw = (char*)Hl[wv];

  short8 a1[4][2], a2[4][2];
#pragma unroll
  for (int mt = 0; mt < 4; mt++){
#pragma unroll
    for (int c = 0; c < 2; c++){
      a1[mt][c] = *(const short8*)(W1cT + (size_t)(mt*16 + e16)*64 + c*32 + g*8);
      a2[mt][c] = *(const short8*)(W2T  + (size_t)(mt*16 + e16)*64 + c*32 + g*8);
    }
  }
  f32x4 b2v[4];
#pragma unroll
  for (int mt = 0; mt < 4; mt++) b2v[mt] = *(const f32x4*)(b2 + mt*16 + g*4);

  int wid = (blockIdx.x*256 + threadIdx.x) >> 6;
  int nw  = (gridDim.x*256) >> 6;
  for (int tile = wid; tile < kE/16; tile += nw){
    int eid = tile*16 + e16;
    int r = row[eid], c = col[eid];
    const unsigned short* erow = ebf + (size_t)eid*64;
    short8 eb0 = *(const short8*)(erow + g*8);
    short8 eb1 = *(const short8*)(erow + 32 + g*8);
    const float* Pr = P + (size_t)r*64;
    const float* Qc = Q + (size_t)c*64;

#pragma unroll
    for (int mt = 0; mt < 4; mt++){
      f32x4 acc = {0.f,0.f,0.f,0.f};
      acc = __builtin_amdgcn_mfma_f32_16x16x32_bf16(a1[mt][0], eb0, acc, 0, 0, 0);
      acc = __builtin_amdgcn_mfma_f32_16x16x32_bf16(a1[mt][1], eb1, acc, 0, 0, 0);
      f32x4 pv = *(const f32x4*)(Pr + mt*16 + g*4);
      f32x4 qv = *(const f32x4*)(Qc + mt*16 + g*4);
      float h0 = fmaxf(acc[0] + pv[0] + qv[0], 0.f);
      float h1 = fmaxf(acc[1] + pv[1] + qv[1], 0.f);
      float h2 = fmaxf(acc[2] + pv[2] + qv[2], 0.f);
      float h3 = fmaxf(acc[3] + pv[3] + qv[3], 0.f);
      uint2 pk; pk.x = pack_bf2(h0, h1); pk.y = pack_bf2(h2, h3);
      // H_lds byte = e16*128 + k*2, k = mt*16 + g*4  -> 8B, XOR-swizzled
      *(uint2*)(Hw + (((e16 << 7) + (mt << 5) + (g << 3)) ^ swz)) = pk;
    }
    // read back as B fragments: k = chunk*32 + g*8 .. +7  (16B contiguous)
    short8 hb0 = *(const short8*)(Hw + (((e16 << 7)      + (g << 4)) ^ swz));
    short8 hb1 = *(const short8*)(Hw + (((e16 << 7) + 64 + (g << 4)) ^ swz));

#pragma unroll
    for (int mt = 0; mt < 4; mt++){
      f32x4 o = {0.f,0.f,0.f,0.f};
      o = __builtin_amdgcn_mfma_f32_16x16x32_bf16(a2[mt][0], hb0, o, 0, 0, 0);
      o = __builtin_amdgcn_mfma_f32_16x16x32_bf16(a2[mt][1], hb1, o, 0, 0, 0);
      float* ep = e + (size_t)eid*64 + mt*16 + g*4;
      f32x4 eo = *(const f32x4*)ep;
      f32x4 ne;
      ne[0] = fmaxf(eo[0] + o[0] + b2v[mt][0], 0.f);
      ne[1] = fmaxf(eo[1] + o[1] + b2v[mt][1], 0.f);
      ne[2] = fmaxf(eo[2] + o[2] + b2v[mt][2], 0.f);
      ne[3] = fmaxf(eo[3] + o[3] + b2v[mt][3], 0.f);
      *(f32x4*)ep = ne;
      uint2 po; po.x = pack_bf2(ne[0], ne[1]); po.y = pack_bf2(ne[2], ne[3]);
      *(uint2*)(ebf + (size_t)eid*64 + mt*16 + g*4) = po;
    }
  }
}

// ---------------- host ----------------
extern "C" void kernel_launch(void* const* d_in, const int* in_sizes, int n_in,
                              void* d_out, int out_size, void* d_ws, size_t ws_size,
                              hipStream_t stream) {
  const float* node_feat = (const float*)d_in[0];
  const int*   edge_idx  = (const int*)d_in[1];
  const float* edge_attr = (const float*)d_in[2];
  const float* W_node = (const float*)d_in[3];
  const float* b_node = (const float*)d_in[4];
  const float* W_edge = (const float*)d_in[5];
  const float* b_edge = (const float*)d_in[6];
  const float* Wl   = (const float*)d_in[7];
  const float* bl   = (const float*)d_in[8];
  const float* Wr   = (const float*)d_in[9];
  const float* br   = (const float*)d_in[10];
  const float* We   = (const float*)d_in[11];
  const float* att  = (const float*)d_in[12];
  const float* cvb  = (const float*)d_in[13];
  const float* lng  = (const float*)d_in[14];
  const float* lnb  = (const float*)d_in[15];
  const float* euW1 = (const float*)d_in[16];
  const float* eub1 = (const float*)d_in[17];
  const float* euW2 = (const float*)d_in[18];
  const float* eub2 = (const float*)d_in[19];

  const int* row = edge_idx;
  const int* col = edge_idx + kE;

  float* x = (float*)d_out;                      // N x 64
  float* e = (float*)d_out + (size_t)kN*kD;      // E x 64

  char* p = (char*)d_ws;
  auto carve = [&](size_t bytes)->void*{
    void* r = (void*)p;
    p += (bytes + 255) & ~(size_t)255;
    return r;
  };
  unsigned short* xl_bf    = (unsigned short*)carve((size_t)kN*kHD*2);
  unsigned short* xr_bf    = (unsigned short*)carve((size_t)kN*kHD*2);
  float* P      = (float*)carve((size_t)kN*kD*4);
  float* Q      = (float*)carve((size_t)kN*kD*4);
  unsigned short* e_bf     = (unsigned short*)carve((size_t)kE*kD*2);
  unsigned short* eloop_bf = (unsigned short*)carve((size_t)kN*kD*2);
  unsigned short* WeT      = (unsigned short*)carve((size_t)3*kHD*kD*2);
  unsigned short* W1cT     = (unsigned short*)carve((size_t)3*kD*kD*2);
  unsigned short* W2T      = (unsigned short*)carve((size_t)3*kD*kD*2);
  float* score  = (float*)carve((size_t)kEN*kH*4);
  float* mmax   = (float*)carve((size_t)kN*kH*4);
  float* ssum   = (float*)carve((size_t)kN*kH*4);
  int* deg      = (int*)carve((size_t)kN*4);
  int* col_start= (int*)carve((size_t)(kN+1)*4);
  int* fill     = (int*)carve((size_t)kN*4);
  int* edge_ids = (int*)carve((size_t)kE*4);

  // CSR build (graph is layer-invariant)
  hipMemsetAsync(deg, 0, (size_t)kN*4, stream);
  hipMemsetAsync(fill, 0, (size_t)kN*4, stream);
  k_deg<<<(kE+255)/256, 256, 0, stream>>>(col, deg);
  k_scan<<<1, 1024, 0, stream>>>(deg, col_start);
  k_fill<<<(kE+255)/256, 256, 0, stream>>>(col, col_start, fill, edge_ids);

  // weight prepack + initial embeddings
  k_prep<<<192, 256, 0, stream>>>(We, WeT);
  k_prep2<<<48, 256, 0, stream>>>(euW1, euW2, W1cT, W2T);
  k_x0<<<(kN*kD+255)/256, 256, 0, stream>>>(node_feat, W_node, b_node, x);
  k_e0<<<(kE*kD+255)/256, 256, 0, stream>>>(edge_attr, W_edge, b_edge, e, e_bf);

  for (int i = 0; i < 3; i++){
    const float* Wl_i  = Wl  + (size_t)i*kD*kHD;
    const float* bl_i  = bl  + (size_t)i*kHD;
    const float* Wr_i  = Wr  + (size_t)i*kD*kHD;
    const float* br_i  = br  + (size_t)i*kHD;
    const float* att_i = att + (size_t)i*kHD;
    const float* cvb_i = cvb + (size_t)i*kD;
    const float* lng_i = lng + (size_t)i*kD;
    const float* lnb_i = lnb + (size_t)i*kD;
    const float* W1_i  = euW1 + (size_t)i*192*64;
    const float* b1_i  = eub1 + (size_t)i*kD;
    const float* b2_i  = eub2 + (size_t)i*kD;
    const unsigned short* WeT_i  = WeT  + (size_t)i*kHD*kD;
    const unsigned short* W1cT_i = W1cT + (size_t)i*kD*kD;
    const unsigned short* W2T_i  = W2T  + (size_t)i*kD*kD;

    k_xlr<<<(kN + XLR_NPB - 1)/XLR_NPB, 256, 0, stream>>>(x, Wl_i, bl_i, Wr_i, br_i,
                                                          xl_bf, xr_bf);
    k_eloop<<<(kN + 3)/4, 256, 0, stream>>>(e_bf, col_start, edge_ids, eloop_bf);
    k_score_mfma<<<2048, 256, 0, stream>>>(e_bf, eloop_bf, xl_bf, xr_bf, row, col,
                                           WeT_i, att_i, score);
    k_segmax<<<(kN*kH + 255)/256, 256, 0, stream>>>(score, col_start, edge_ids, mmax, ssum);
    k_agg_ln<<<kN, 256, 0, stream>>>(xl_bf, score, row, col_start, edge_ids, mmax, ssum,
                                     cvb_i, lng_i, lnb_i, x);
    k_pq<<<(kN + PQ_NPB - 1)/PQ_NPB, 256, 0, stream>>>(x, W1_i, b1_i, P, Q);
    k_mlp_mfma<<<2048, 256, 0, stream>>>(e, e_bf, P, Q, W1cT_i, W2T_i, b2_i, row, col);
  }
}

// Round 5
// 1234.146 us; speedup vs baseline: 2.7694x; 1.2934x over previous
//
#include <hip/hip_runtime.h>
#include <hip/hip_bf16.h>
#include <cstdint>
#include <cstddef>

// Problem constants (fixed by the reference).
constexpr int kN  = 25000;
constexpr int kE  = 400000;
constexpr int kEN = kE + kN;
constexpr int kD  = 64;
constexpr int kH  = 4;
constexpr int kHD = 256;       // H * DH

typedef __attribute__((ext_vector_type(8))) short short8;
typedef __attribute__((ext_vector_type(4))) float f32x4;

__device__ __forceinline__ float lrelu02(float x){ return x > 0.f ? x : 0.2f*x; }
__device__ __forceinline__ unsigned short f2bf(float f){
  __hip_bfloat16 h = __float2bfloat16(f);
  return *reinterpret_cast<unsigned short*>(&h);
}
__device__ __forceinline__ float bf2f(unsigned short u){
  return __uint_as_float(((unsigned)u) << 16);
}
__device__ __forceinline__ float bf_lo(unsigned u){ return __uint_as_float(u << 16); }
__device__ __forceinline__ float bf_hi(unsigned u){ return __uint_as_float(u & 0xffff0000u); }
__device__ __forceinline__ unsigned pack_bf2(float a, float b){
  return ((unsigned)f2bf(a)) | (((unsigned)f2bf(b)) << 16);
}

// ---------------- CSR build ----------------
__global__ void k_deg(const int* __restrict__ col, int* __restrict__ deg){
  int i = blockIdx.x*256 + threadIdx.x;
  if (i < kE) atomicAdd(&deg[col[i]], 1);
}

__global__ void k_scan(const int* __restrict__ deg, int* __restrict__ col_start){
  __shared__ int lds[1024];
  __shared__ int carry_s;
  int t = threadIdx.x;
  if (t == 0) carry_s = 0;
  __syncthreads();
  for (int base = 0; base < kN; base += 1024){
    int v = (base + t < kN) ? deg[base + t] : 0;
    lds[t] = v; __syncthreads();
    for (int off = 1; off < 1024; off <<= 1){
      int add = (t >= off) ? lds[t - off] : 0;
      __syncthreads();
      lds[t] += add;
      __syncthreads();
    }
    int incl = lds[t];
    int carry = carry_s;
    if (base + t < kN) col_start[base + t] = carry + incl - v;
    __syncthreads();
    if (t == 0) carry_s = carry + lds[1023];
    __syncthreads();
  }
  if (t == 0) col_start[kN] = carry_s;
}

__global__ void k_fill(const int* __restrict__ col, const int* __restrict__ col_start,
                       int* __restrict__ fill, int* __restrict__ edge_ids){
  int i = blockIdx.x*256 + threadIdx.x;
  if (i < kE){
    int c = col[i];
    int p = atomicAdd(&fill[c], 1);
    edge_ids[col_start[c] + p] = i;
  }
}

// rowp/colp: row/col in permuted (CSR) edge order
__global__ void k_permrc(const int* __restrict__ edge_ids, const int* __restrict__ row,
                         const int* __restrict__ col, int* __restrict__ rowp,
                         int* __restrict__ colp){
  int p = blockIdx.x*256 + threadIdx.x;
  if (p < kE){
    int eid = edge_ids[p];
    rowp[p] = row[eid];
    colp[p] = col[eid];
  }
}

// ---------------- weight prepack ----------------
// WeT[l][j][k] = bf16(We[l][k][j])   (j in [0,256), k in [0,64))
__global__ void k_prep(const float* __restrict__ We, unsigned short* __restrict__ WeT){
  int idx = blockIdx.x*256 + threadIdx.x;
  if (idx >= 3*256*64) return;
  int l = idx >> 14, j = (idx >> 6) & 255, k = idx & 63;
  WeT[idx] = f2bf(We[(size_t)l*16384 + k*256 + j]);
}

// W1cT[l][d][k] = bf16(euW1[l][128+k][d]);  W2T[l][d][k] = bf16(euW2[l][k][d])
__global__ void k_prep2(const float* __restrict__ euW1, const float* __restrict__ euW2,
                        unsigned short* __restrict__ W1cT, unsigned short* __restrict__ W2T){
  int idx = blockIdx.x*256 + threadIdx.x;
  if (idx >= 3*64*64) return;
  int l = idx >> 12, rem = idx & 4095, d = rem >> 6, k = rem & 63;
  W1cT[idx] = f2bf(euW1[(size_t)l*192*64 + (size_t)(128+k)*64 + d]);
  W2T[idx]  = f2bf(euW2[(size_t)l*64*64  + (size_t)k*64 + d]);
}

// ---------------- initial embeddings ----------------
__global__ void k_x0(const float* __restrict__ nf, const float* __restrict__ W,
                     const float* __restrict__ b, float* __restrict__ x){
  int i = blockIdx.x*256 + threadIdx.x;
  if (i >= kN*kD) return;
  int n = i >> 6, d = i & 63;
  float acc = b[d];
#pragma unroll
  for (int k = 0; k < 16; k++) acc += nf[n*16 + k] * W[k*64 + d];
  x[i] = fmaxf(acc, 0.f);
}

// e0 in PERMUTED order: e_perm[p] = relu(edge_attr[perm[p]] @ W_edge + b)
__global__ void k_e0p(const int* __restrict__ edge_ids,
                      const float* __restrict__ ea, const float* __restrict__ W,
                      const float* __restrict__ b, float* __restrict__ e_perm,
                      unsigned short* __restrict__ ebf_perm){
  long long i = (long long)blockIdx.x*256 + threadIdx.x;
  if (i >= (long long)kE*kD) return;
  int p = (int)(i >> 6), d = (int)(i & 63);
  int eid = edge_ids[p];
  float acc = b[d];
#pragma unroll
  for (int k = 0; k < 4; k++) acc += ea[eid*4 + k] * W[k*64 + d];
  float v = fmaxf(acc, 0.f);
  e_perm[i] = v; ebf_perm[i] = f2bf(v);
}

// ---------------- per-layer: xl_bf = bf16(x@Wl+bl), xr_bf = bf16(x@Wr+br) ----------------
#define XLR_NPB 8
__global__ __launch_bounds__(256) void k_xlr(const float* __restrict__ x,
    const float* __restrict__ Wl, const float* __restrict__ bl,
    const float* __restrict__ Wr, const float* __restrict__ br,
    unsigned short* __restrict__ xl_bf, unsigned short* __restrict__ xr_bf){
  __shared__ float xs[XLR_NPB*64];
  int j = threadIdx.x;
  int n0 = blockIdx.x * XLR_NPB;
  for (int i = j; i < XLR_NPB*64; i += 256){
    int n = n0 + (i >> 6);
    xs[i] = (n < kN) ? x[(size_t)n*64 + (i & 63)] : 0.f;
  }
  __syncthreads();
  float accl[XLR_NPB], accr[XLR_NPB];
  float blv = bl[j], brv = br[j];
#pragma unroll
  for (int t = 0; t < XLR_NPB; t++){ accl[t] = blv; accr[t] = brv; }
  for (int k = 0; k < 64; k++){
    float wl = Wl[k*kHD + j], wr = Wr[k*kHD + j];
#pragma unroll
    for (int t = 0; t < XLR_NPB; t++){
      float xv = xs[t*64 + k];
      accl[t] += xv * wl; accr[t] += xv * wr;
    }
  }
#pragma unroll
  for (int t = 0; t < XLR_NPB; t++){
    int n = n0 + t;
    if (n < kN){
      xl_bf[(size_t)n*kHD + j] = f2bf(accl[t]);
      xr_bf[(size_t)n*kHD + j] = f2bf(accr[t]);
    }
  }
}

// ---------------- per-layer: e_loop (bf16) = mean of incoming e rows (contiguous) ------
__global__ __launch_bounds__(256) void k_eloop(const unsigned short* __restrict__ ebf_perm,
    const int* __restrict__ col_start, unsigned short* __restrict__ eloop_bf){
  int wave = threadIdx.x >> 6, lane = threadIdx.x & 63;
  int n = blockIdx.x*4 + wave;
  if (n >= kN) return;
  int s0 = col_start[n], s1 = col_start[n+1];
  float acc = 0.f;
  for (int p = s0; p < s1; p++)
    acc += bf2f(ebf_perm[(size_t)p*64 + lane]);
  int dg = s1 - s0;
  eloop_bf[(size_t)n*64 + lane] = f2bf(acc / (float)(dg > 0 ? dg : 1));
}

// ---------------- per-layer: MFMA score kernel (wave = head, A in registers) ----------
// Block = 4 waves; wave h computes head h for the block's 16-edge tile.
// A fragments (WeT slice for head h) are loop-invariant registers.
__global__ __launch_bounds__(256) void k_score_mfma(
    const unsigned short* __restrict__ ebf_perm, // [E][64] permuted
    const unsigned short* __restrict__ eloop_bf, // [N][64]
    const unsigned short* __restrict__ xl_bf,    // [N][256]
    const unsigned short* __restrict__ xr_bf,    // [N][256]
    const int* __restrict__ rowp, const int* __restrict__ colp,
    const unsigned short* __restrict__ WeT,      // [256][64] bf16
    const float* __restrict__ att,               // [4][64]
    float* __restrict__ score)                   // [EN][4] permuted
{
  int lane = threadIdx.x & 63;
  int h    = threadIdx.x >> 6;   // wave id == head
  int e16  = lane & 15;          // edge-in-tile (B col / C col / A row)
  int kb   = lane >> 4;          // k-block (A/B), row-group (C)

  short8 A[4][2];
  f32x4 atv[4];
#pragma unroll
  for (int mt = 0; mt < 4; mt++){
    const unsigned short* arow = WeT + (size_t)(h*64 + mt*16 + e16)*64 + kb*8;
    A[mt][0] = *(const short8*)(arow);
    A[mt][1] = *(const short8*)(arow + 32);
    atv[mt] = *(const f32x4*)(att + h*64 + mt*16 + kb*4);
  }

  constexpr int NT = (kEN + 15)/16;
  for (int tile = blockIdx.x; tile < NT; tile += gridDim.x){
    int p = tile*16 + e16;
    int pc = (p < kEN) ? p : 0;
    bool isE = pc < kE;
    const unsigned short* erow = isE ? (ebf_perm + (size_t)pc*64)
                                     : (eloop_bf + (size_t)(pc - kE)*64);
    short8 b0 = *(const short8*)(erow + kb*8);
    short8 b1 = *(const short8*)(erow + 32 + kb*8);
    int r = isE ? rowp[pc] : (pc - kE);
    int c = isE ? colp[pc] : (pc - kE);
    const unsigned short* xlr_ = xl_bf + (size_t)r*kHD + h*64;
    const unsigned short* xrc_ = xr_bf + (size_t)c*kHD + h*64;

    uint2 xlu[4], xru[4];
#pragma unroll
    for (int mt = 0; mt < 4; mt++){
      xlu[mt] = *(const uint2*)(xlr_ + mt*16 + kb*4);
      xru[mt] = *(const uint2*)(xrc_ + mt*16 + kb*4);
    }
    float sc = 0.f;
#pragma unroll
    for (int mt = 0; mt < 4; mt++){
      f32x4 acc = {0.f,0.f,0.f,0.f};
      acc = __builtin_amdgcn_mfma_f32_16x16x32_bf16(A[mt][0], b0, acc, 0, 0, 0);
      acc = __builtin_amdgcn_mfma_f32_16x16x32_bf16(A[mt][1], b1, acc, 0, 0, 0);
      float xl0 = bf_lo(xlu[mt].x), xl1 = bf_hi(xlu[mt].x);
      float xl2 = bf_lo(xlu[mt].y), xl3 = bf_hi(xlu[mt].y);
      float xr0 = bf_lo(xru[mt].x), xr1 = bf_hi(xru[mt].x);
      float xr2 = bf_lo(xru[mt].y), xr3 = bf_hi(xru[mt].y);
      sc += lrelu02(acc[0] + xl0 + xr0) * atv[mt][0];
      sc += lrelu02(acc[1] + xl1 + xr1) * atv[mt][1];
      sc += lrelu02(acc[2] + xl2 + xr2) * atv[mt][2];
      sc += lrelu02(acc[3] + xl3 + xr3) * atv[mt][3];
    }
    sc += __shfl_xor(sc, 16);
    sc += __shfl_xor(sc, 32);
    int wp = tile*16 + lane;
    if (lane < 16 && wp < kEN) score[(size_t)wp*kH + h] = sc;
  }
}

// ---------------- per-layer: segment max & expsum (contiguous score) ----------------
__global__ void k_segmax(const float* __restrict__ score,
    const int* __restrict__ col_start,
    float* __restrict__ mmax, float* __restrict__ ssum){
  int i = blockIdx.x*256 + threadIdx.x;
  if (i >= kN*kH) return;
  int n = i >> 2, h = i & 3;
  float selfsc = score[(size_t)(kE + n)*kH + h];
  float m = selfsc;
  int s0 = col_start[n], s1 = col_start[n+1];
  for (int p = s0; p < s1; p++)
    m = fmaxf(m, score[(size_t)p*kH + h]);
  float s = expf(selfsc - m);
  for (int p = s0; p < s1; p++)
    s += expf(score[(size_t)p*kH + h] - m);
  mmax[i] = m; ssum[i] = s;
}

// ---------------- per-layer: aggregate + head-mean + residual + LN + relu --------------
__global__ __launch_bounds__(256) void k_agg_ln(
    const unsigned short* __restrict__ xl_bf, const float* __restrict__ score,
    const int* __restrict__ rowp, const int* __restrict__ col_start,
    const float* __restrict__ mmax, const float* __restrict__ ssum,
    const float* __restrict__ conv_b, const float* __restrict__ ln_g,
    const float* __restrict__ ln_b, float* __restrict__ x){
  int n = blockIdx.x;
  int j = threadIdx.x, h = j >> 6, d = j & 63;
  float m = mmax[n*4 + h];
  float inv = 1.f / ssum[n*4 + h];
  float a = expf(score[(size_t)(kE + n)*kH + h] - m) * inv;
  float acc = a * bf2f(xl_bf[(size_t)n*kHD + j]);
  int s0 = col_start[n], s1 = col_start[n+1];
  for (int p = s0; p < s1; p++){
    int r = rowp[p];
    float ae = expf(score[(size_t)p*kH + h] - m) * inv;
    acc += ae * bf2f(xl_bf[(size_t)r*kHD + j]);
  }
  __shared__ float lds[256];
  lds[j] = acc; __syncthreads();
  if (j < 64){
    float upd = (lds[d] + lds[64+d] + lds[128+d] + lds[192+d]) * 0.25f + conv_b[d];
    float y = x[(size_t)n*64 + d] + upd;
    float mu = y;
#pragma unroll
    for (int off = 32; off; off >>= 1) mu += __shfl_xor(mu, off);
    mu *= (1.f/64.f);
    float diff = y - mu;
    float var = diff * diff;
#pragma unroll
    for (int off = 32; off; off >>= 1) var += __shfl_xor(var, off);
    var *= (1.f/64.f);
    float out = diff * rsqrtf(var + 1e-5f) * ln_g[d] + ln_b[d];
    x[(size_t)n*64 + d] = fmaxf(out, 0.f);
  }
}

// ---------------- per-layer: P = x@W1a + b1, Q = x@W1b ----------------
#define PQ_NPB 16
__global__ __launch_bounds__(256) void k_pq(const float* __restrict__ x,
    const float* __restrict__ W1, const float* __restrict__ b1,
    float* __restrict__ P, float* __restrict__ Q){
  __shared__ float xs[PQ_NPB*64];
  int tid = threadIdx.x;
  int j = tid & 63;
  int s = tid >> 6;
  int n0 = blockIdx.x * PQ_NPB;
  for (int i = tid; i < PQ_NPB*64; i += 256){
    int n = n0 + (i >> 6);
    xs[i] = (n < kN) ? x[(size_t)n*64 + (i & 63)] : 0.f;
  }
  __syncthreads();
  float accP[4], accQ[4];
  float b1v = b1[j];
#pragma unroll
  for (int t = 0; t < 4; t++){ accP[t] = b1v; accQ[t] = 0.f; }
  for (int k = 0; k < 64; k++){
    float wa = W1[k*64 + j];
    float wb = W1[(64 + k)*64 + j];
#pragma unroll
    for (int t = 0; t < 4; t++){
      float xv = xs[(s*4 + t)*64 + k];
      accP[t] += xv * wa; accQ[t] += xv * wb;
    }
  }
#pragma unroll
  for (int t = 0; t < 4; t++){
    int n = n0 + s*4 + t;
    if (n < kN){ P[(size_t)n*64 + j] = accP[t]; Q[(size_t)n*64 + j] = accQ[t]; }
  }
}

// ---------------- per-layer: edge MLP via MFMA (permuted edge space) ----------------
// Layers 0,1: residual from e_perm f32, write e_perm f32 + ebf_perm.
// Layer 2 (eout_perm==NULL): residual from ebf_perm, scatter f32 to d_out via edge_ids.
__global__ __launch_bounds__(256) void k_mlp_mfma(
    const float* __restrict__ e_perm_in,
    unsigned short* __restrict__ ebf_perm,
    float* __restrict__ eout_perm,
    float* __restrict__ eout_scatter,
    const int* __restrict__ edge_ids,
    const float* __restrict__ P, const float* __restrict__ Q,
    const unsigned short* __restrict__ W1cT,  // [64 d][64 k] bf16
    const unsigned short* __restrict__ W2T,   // [64 d][64 k] bf16
    const float* __restrict__ b2,
    const int* __restrict__ rowp, const int* __restrict__ colp)
{
  __shared__ unsigned short Hl[4][1024];      // 2KB per wave
  int lane = threadIdx.x & 63, wv = threadIdx.x >> 6;
  int e16 = lane & 15, g = lane >> 4;
  int swz = (e16 & 7) << 4;
  char* Hw = (char*)Hl[wv];
  bool perm_out = (eout_perm != nullptr);

  short8 a1[4][2], a2[4][2];
#pragma unroll
  for (int mt = 0; mt < 4; mt++){
#pragma unroll
    for (int c = 0; c < 2; c++){
      a1[mt][c] = *(const short8*)(W1cT + (size_t)(mt*16 + e16)*64 + c*32 + g*8);
      a2[mt][c] = *(const short8*)(W2T  + (size_t)(mt*16 + e16)*64 + c*32 + g*8);
    }
  }
  f32x4 b2v[4];
#pragma unroll
  for (int mt = 0; mt < 4; mt++) b2v[mt] = *(const f32x4*)(b2 + mt*16 + g*4);

  int wid = (blockIdx.x*256 + threadIdx.x) >> 6;
  int nw  = (gridDim.x*256) >> 6;
  for (int tile = wid; tile < kE/16; tile += nw){
    int p = tile*16 + e16;
    int r = rowp[p], c = colp[p];
    const unsigned short* erow = ebf_perm + (size_t)p*64;
    short8 eb0 = *(const short8*)(erow + g*8);
    short8 eb1 = *(const short8*)(erow + 32 + g*8);
    const float* Pr = P + (size_t)r*64;
    const float* Qc = Q + (size_t)c*64;

#pragma unroll
    for (int mt = 0; mt < 4; mt++){
      f32x4 acc = {0.f,0.f,0.f,0.f};
      acc = __builtin_amdgcn_mfma_f32_16x16x32_bf16(a1[mt][0], eb0, acc, 0, 0, 0);
      acc = __builtin_amdgcn_mfma_f32_16x16x32_bf16(a1[mt][1], eb1, acc, 0, 0, 0);
      f32x4 pv = *(const f32x4*)(Pr + mt*16 + g*4);
      f32x4 qv = *(const f32x4*)(Qc + mt*16 + g*4);
      float h0 = fmaxf(acc[0] + pv[0] + qv[0], 0.f);
      float h1 = fmaxf(acc[1] + pv[1] + qv[1], 0.f);
      float h2 = fmaxf(acc[2] + pv[2] + qv[2], 0.f);
      float h3 = fmaxf(acc[3] + pv[3] + qv[3], 0.f);
      uint2 pk; pk.x = pack_bf2(h0, h1); pk.y = pack_bf2(h2, h3);
      *(uint2*)(Hw + (((e16 << 7) + (mt << 5) + (g << 3)) ^ swz)) = pk;
    }
    short8 hb0 = *(const short8*)(Hw + (((e16 << 7)      + (g << 4)) ^ swz));
    short8 hb1 = *(const short8*)(Hw + (((e16 << 7) + 64 + (g << 4)) ^ swz));

    int oe = perm_out ? 0 : edge_ids[p];
#pragma unroll
    for (int mt = 0; mt < 4; mt++){
      f32x4 o = {0.f,0.f,0.f,0.f};
      o = __builtin_amdgcn_mfma_f32_16x16x32_bf16(a2[mt][0], hb0, o, 0, 0, 0);
      o = __builtin_amdgcn_mfma_f32_16x16x32_bf16(a2[mt][1], hb1, o, 0, 0, 0);
      size_t off = (size_t)p*64 + mt*16 + g*4;
      f32x4 eo;
      if (perm_out){
        eo = *(const f32x4*)(e_perm_in + off);
      } else {
        uint2 u = *(const uint2*)(ebf_perm + off);
        eo[0] = bf_lo(u.x); eo[1] = bf_hi(u.x); eo[2] = bf_lo(u.y); eo[3] = bf_hi(u.y);
      }
      f32x4 ne;
      ne[0] = fmaxf(eo[0] + o[0] + b2v[mt][0], 0.f);
      ne[1] = fmaxf(eo[1] + o[1] + b2v[mt][1], 0.f);
      ne[2] = fmaxf(eo[2] + o[2] + b2v[mt][2], 0.f);
      ne[3] = fmaxf(eo[3] + o[3] + b2v[mt][3], 0.f);
      if (perm_out){
        *(f32x4*)(eout_perm + off) = ne;
        uint2 po; po.x = pack_bf2(ne[0], ne[1]); po.y = pack_bf2(ne[2], ne[3]);
        *(uint2*)(ebf_perm + off) = po;
      } else {
        *(f32x4*)(eout_scatter + (size_t)oe*64 + mt*16 + g*4) = ne;
      }
    }
  }
}

// ---------------- host ----------------
extern "C" void kernel_launch(void* const* d_in, const int* in_sizes, int n_in,
                              void* d_out, int out_size, void* d_ws, size_t ws_size,
                              hipStream_t stream) {
  const float* node_feat = (const float*)d_in[0];
  const int*   edge_idx  = (const int*)d_in[1];
  const float* edge_attr = (const float*)d_in[2];
  const float* W_node = (const float*)d_in[3];
  const float* b_node = (const float*)d_in[4];
  const float* W_edge = (const float*)d_in[5];
  const float* b_edge = (const float*)d_in[6];
  const float* Wl   = (const float*)d_in[7];
  const float* bl   = (const float*)d_in[8];
  const float* Wr   = (const float*)d_in[9];
  const float* br   = (const float*)d_in[10];
  const float* We   = (const float*)d_in[11];
  const float* att  = (const float*)d_in[12];
  const float* cvb  = (const float*)d_in[13];
  const float* lng  = (const float*)d_in[14];
  const float* lnb  = (const float*)d_in[15];
  const float* euW1 = (const float*)d_in[16];
  const float* eub1 = (const float*)d_in[17];
  const float* euW2 = (const float*)d_in[18];
  const float* eub2 = (const float*)d_in[19];

  const int* row = edge_idx;
  const int* col = edge_idx + kE;

  float* x = (float*)d_out;                       // N x 64
  float* e_out = (float*)d_out + (size_t)kN*kD;   // E x 64 (permuted during layers 0-1)

  char* p = (char*)d_ws;
  auto carve = [&](size_t bytes)->void*{
    void* r = (void*)p;
    p += (bytes + 255) & ~(size_t)255;
    return r;
  };
  unsigned short* xl_bf    = (unsigned short*)carve((size_t)kN*kHD*2);
  unsigned short* xr_bf    = (unsigned short*)carve((size_t)kN*kHD*2);
  float* P      = (float*)carve((size_t)kN*kD*4);
  float* Q      = (float*)carve((size_t)kN*kD*4);
  unsigned short* ebf_perm = (unsigned short*)carve((size_t)kE*kD*2);
  unsigned short* eloop_bf = (unsigned short*)carve((size_t)kN*kD*2);
  unsigned short* WeT      = (unsigned short*)carve((size_t)3*kHD*kD*2);
  unsigned short* W1cT     = (unsigned short*)carve((size_t)3*kD*kD*2);
  unsigned short* W2T      = (unsigned short*)carve((size_t)3*kD*kD*2);
  float* score  = (float*)carve((size_t)kEN*kH*4);
  float* mmax   = (float*)carve((size_t)kN*kH*4);
  float* ssum   = (float*)carve((size_t)kN*kH*4);
  int* deg      = (int*)carve((size_t)kN*4);
  int* col_start= (int*)carve((size_t)(kN+1)*4);
  int* fill     = (int*)carve((size_t)kN*4);
  int* edge_ids = (int*)carve((size_t)kE*4);
  int* rowp     = (int*)carve((size_t)kE*4);
  int* colp     = (int*)carve((size_t)kE*4);

  // CSR build (graph is layer-invariant)
  hipMemsetAsync(deg, 0, (size_t)kN*4, stream);
  hipMemsetAsync(fill, 0, (size_t)kN*4, stream);
  k_deg<<<(kE+255)/256, 256, 0, stream>>>(col, deg);
  k_scan<<<1, 1024, 0, stream>>>(deg, col_start);
  k_fill<<<(kE+255)/256, 256, 0, stream>>>(col, col_start, fill, edge_ids);
  k_permrc<<<(kE+255)/256, 256, 0, stream>>>(edge_ids, row, col, rowp, colp);

  // weight prepack + initial embeddings
  k_prep<<<192, 256, 0, stream>>>(We, WeT);
  k_prep2<<<48, 256, 0, stream>>>(euW1, euW2, W1cT, W2T);
  k_x0<<<(kN*kD+255)/256, 256, 0, stream>>>(node_feat, W_node, b_node, x);
  k_e0p<<<(int)(((size_t)kE*kD+255)/256), 256, 0, stream>>>(edge_ids, edge_attr, W_edge,
                                                            b_edge, e_out, ebf_perm);

  for (int i = 0; i < 3; i++){
    const float* Wl_i  = Wl  + (size_t)i*kD*kHD;
    const float* bl_i  = bl  + (size_t)i*kHD;
    const float* Wr_i  = Wr  + (size_t)i*kD*kHD;
    const float* br_i  = br  + (size_t)i*kHD;
    const float* att_i = att + (size_t)i*kHD;
    const float* cvb_i = cvb + (size_t)i*kD;
    const float* lng_i = lng + (size_t)i*kD;
    const float* lnb_i = lnb + (size_t)i*kD;
    const float* W1_i  = euW1 + (size_t)i*192*64;
    const float* b1_i  = eub1 + (size_t)i*kD;
    const float* b2_i  = eub2 + (size_t)i*kD;
    const unsigned short* WeT_i  = WeT  + (size_t)i*kHD*kD;
    const unsigned short* W1cT_i = W1cT + (size_t)i*kD*kD;
    const unsigned short* W2T_i  = W2T  + (size_t)i*kD*kD;

    k_xlr<<<(kN + XLR_NPB - 1)/XLR_NPB, 256, 0, stream>>>(x, Wl_i, bl_i, Wr_i, br_i,
                                                          xl_bf, xr_bf);
    k_eloop<<<(kN + 3)/4, 256, 0, stream>>>(ebf_perm, col_start, eloop_bf);
    k_score_mfma<<<2048, 256, 0, stream>>>(ebf_perm, eloop_bf, xl_bf, xr_bf,
                                           rowp, colp, WeT_i, att_i, score);
    k_segmax<<<(kN*kH + 255)/256, 256, 0, stream>>>(score, col_start, mmax, ssum);
    k_agg_ln<<<kN, 256, 0, stream>>>(xl_bf, score, rowp, col_start, mmax, ssum,
                                     cvb_i, lng_i, lnb_i, x);
    k_pq<<<(kN + PQ_NPB - 1)/PQ_NPB, 256, 0, stream>>>(x, W1_i, b1_i, P, Q);
    k_mlp_mfma<<<2048, 256, 0, stream>>>(e_out, ebf_perm,
                                         (i < 2) ? e_out : nullptr, e_out,
                                         edge_ids, P, Q, W1cT_i, W2T_i, b2_i,
                                         rowp, colp);
  }
}

// Round 6
// 1059.686 us; speedup vs baseline: 3.2253x; 1.1646x over previous
//
#include <hip/hip_runtime.h>
#include <hip/hip_bf16.h>
#include <cstdint>
#include <cstddef>

// Problem constants (fixed by the reference).
constexpr int kN  = 25000;
constexpr int kE  = 400000;
constexpr int kEN = kE + kN;
constexpr int kD  = 64;
constexpr int kH  = 4;
constexpr int kHD = 256;       // H * DH

typedef __attribute__((ext_vector_type(8))) short short8;
typedef __attribute__((ext_vector_type(4))) float f32x4;

__device__ __forceinline__ float lrelu02(float x){ return x > 0.f ? x : 0.2f*x; }
__device__ __forceinline__ unsigned short f2bf(float f){
  __hip_bfloat16 h = __float2bfloat16(f);
  return *reinterpret_cast<unsigned short*>(&h);
}
__device__ __forceinline__ float bf2f(unsigned short u){
  return __uint_as_float(((unsigned)u) << 16);
}
__device__ __forceinline__ float bf_lo(unsigned u){ return __uint_as_float(u << 16); }
__device__ __forceinline__ float bf_hi(unsigned u){ return __uint_as_float(u & 0xffff0000u); }
__device__ __forceinline__ unsigned pack_bf2(float a, float b){
  return ((unsigned)f2bf(a)) | (((unsigned)f2bf(b)) << 16);
}

// ---------------- CSR build ----------------
__global__ void k_deg(const int* __restrict__ col, int* __restrict__ deg){
  int i = blockIdx.x*256 + threadIdx.x;
  if (i < kE) atomicAdd(&deg[col[i]], 1);
}

__global__ void k_scan(const int* __restrict__ deg, int* __restrict__ col_start){
  __shared__ int lds[1024];
  __shared__ int carry_s;
  int t = threadIdx.x;
  if (t == 0) carry_s = 0;
  __syncthreads();
  for (int base = 0; base < kN; base += 1024){
    int v = (base + t < kN) ? deg[base + t] : 0;
    lds[t] = v; __syncthreads();
    for (int off = 1; off < 1024; off <<= 1){
      int add = (t >= off) ? lds[t - off] : 0;
      __syncthreads();
      lds[t] += add;
      __syncthreads();
    }
    int incl = lds[t];
    int carry = carry_s;
    if (base + t < kN) col_start[base + t] = carry + incl - v;
    __syncthreads();
    if (t == 0) carry_s = carry + lds[1023];
    __syncthreads();
  }
  if (t == 0) col_start[kN] = carry_s;
}

__global__ void k_fill(const int* __restrict__ col, const int* __restrict__ col_start,
                       int* __restrict__ fill, int* __restrict__ edge_ids){
  int i = blockIdx.x*256 + threadIdx.x;
  if (i < kE){
    int c = col[i];
    int p = atomicAdd(&fill[c], 1);
    edge_ids[col_start[c] + p] = i;
  }
}

// rowp/colp: row/col in permuted (CSR) edge order
__global__ void k_permrc(const int* __restrict__ edge_ids, const int* __restrict__ row,
                         const int* __restrict__ col, int* __restrict__ rowp,
                         int* __restrict__ colp){
  int p = blockIdx.x*256 + threadIdx.x;
  if (p < kE){
    int eid = edge_ids[p];
    rowp[p] = row[eid];
    colp[p] = col[eid];
  }
}

// ---------------- weight prepack ----------------
// WeT[l][j][k] = bf16(We[l][k][j])   (j in [0,256), k in [0,64))
__global__ void k_prep(const float* __restrict__ We, unsigned short* __restrict__ WeT){
  int idx = blockIdx.x*256 + threadIdx.x;
  if (idx >= 3*256*64) return;
  int l = idx >> 14, j = (idx >> 6) & 255, k = idx & 63;
  WeT[idx] = f2bf(We[(size_t)l*16384 + k*256 + j]);
}

// W1cT[l][d][k] = bf16(euW1[l][128+k][d]);  W2T[l][d][k] = bf16(euW2[l][k][d])
__global__ void k_prep2(const float* __restrict__ euW1, const float* __restrict__ euW2,
                        unsigned short* __restrict__ W1cT, unsigned short* __restrict__ W2T){
  int idx = blockIdx.x*256 + threadIdx.x;
  if (idx >= 3*64*64) return;
  int l = idx >> 12, rem = idx & 4095, d = rem >> 6, k = rem & 63;
  W1cT[idx] = f2bf(euW1[(size_t)l*192*64 + (size_t)(128+k)*64 + d]);
  W2T[idx]  = f2bf(euW2[(size_t)l*64*64  + (size_t)k*64 + d]);
}

// ---------------- initial embeddings ----------------
__global__ void k_x0(const float* __restrict__ nf, const float* __restrict__ W,
                     const float* __restrict__ b, float* __restrict__ x){
  int i = blockIdx.x*256 + threadIdx.x;
  if (i >= kN*kD) return;
  int n = i >> 6, d = i & 63;
  float acc = b[d];
#pragma unroll
  for (int k = 0; k < 16; k++) acc += nf[n*16 + k] * W[k*64 + d];
  x[i] = fmaxf(acc, 0.f);
}

// e0 in PERMUTED order, bf16 only
__global__ void k_e0p(const int* __restrict__ edge_ids,
                      const float* __restrict__ ea, const float* __restrict__ W,
                      const float* __restrict__ b,
                      unsigned short* __restrict__ ebf_perm){
  long long i = (long long)blockIdx.x*256 + threadIdx.x;
  if (i >= (long long)kE*kD) return;
  int p = (int)(i >> 6), d = (int)(i & 63);
  int eid = edge_ids[p];
  float acc = b[d];
#pragma unroll
  for (int k = 0; k < 4; k++) acc += ea[eid*4 + k] * W[k*64 + d];
  ebf_perm[i] = f2bf(fmaxf(acc, 0.f));
}

// ---------------- per-layer: xl_bf = bf16(x@Wl+bl), xr_bf = bf16(x@Wr+br) ----------------
#define XLR_NPB 8
__global__ __launch_bounds__(256) void k_xlr(const float* __restrict__ x,
    const float* __restrict__ Wl, const float* __restrict__ bl,
    const float* __restrict__ Wr, const float* __restrict__ br,
    unsigned short* __restrict__ xl_bf, unsigned short* __restrict__ xr_bf){
  __shared__ float xs[XLR_NPB*64];
  int j = threadIdx.x;
  int n0 = blockIdx.x * XLR_NPB;
  for (int i = j; i < XLR_NPB*64; i += 256){
    int n = n0 + (i >> 6);
    xs[i] = (n < kN) ? x[(size_t)n*64 + (i & 63)] : 0.f;
  }
  __syncthreads();
  float accl[XLR_NPB], accr[XLR_NPB];
  float blv = bl[j], brv = br[j];
#pragma unroll
  for (int t = 0; t < XLR_NPB; t++){ accl[t] = blv; accr[t] = brv; }
  for (int k = 0; k < 64; k++){
    float wl = Wl[k*kHD + j], wr = Wr[k*kHD + j];
#pragma unroll
    for (int t = 0; t < XLR_NPB; t++){
      float xv = xs[t*64 + k];
      accl[t] += xv * wl; accr[t] += xv * wr;
    }
  }
#pragma unroll
  for (int t = 0; t < XLR_NPB; t++){
    int n = n0 + t;
    if (n < kN){
      xl_bf[(size_t)n*kHD + j] = f2bf(accl[t]);
      xr_bf[(size_t)n*kHD + j] = f2bf(accr[t]);
    }
  }
}

// ---------------- per-layer: e_loop (bf16) = mean of incoming e rows (contiguous) ------
__global__ __launch_bounds__(256) void k_eloop(const unsigned short* __restrict__ ebf_perm,
    const int* __restrict__ col_start, unsigned short* __restrict__ eloop_bf){
  int wave = threadIdx.x >> 6, lane = threadIdx.x & 63;
  int n = blockIdx.x*4 + wave;
  if (n >= kN) return;
  int s0 = col_start[n], s1 = col_start[n+1];
  float acc = 0.f;
  for (int p = s0; p < s1; p++)
    acc += bf2f(ebf_perm[(size_t)p*64 + lane]);
  int dg = s1 - s0;
  eloop_bf[(size_t)n*64 + lane] = f2bf(acc / (float)(dg > 0 ? dg : 1));
}

// ---------------- per-layer: MFMA score kernel, depth-2 software pipeline ----------
struct STile {
  short8 b0, b1;
  uint2 xlu[4], xru[4];
};

__device__ __forceinline__ void s_load(int tile, STile& f, int e16, int kb, int h,
    const unsigned short* __restrict__ ebf_perm,
    const unsigned short* __restrict__ eloop_bf,
    const unsigned short* __restrict__ xl_bf,
    const unsigned short* __restrict__ xr_bf,
    const int* __restrict__ rowp, const int* __restrict__ colp)
{
  int p = tile*16 + e16;
  int pc = (p < kEN) ? p : 0;
  bool isE = pc < kE;
  const unsigned short* erow = isE ? (ebf_perm + (size_t)pc*64)
                                   : (eloop_bf + (size_t)(pc - kE)*64);
  f.b0 = *(const short8*)(erow + kb*8);
  f.b1 = *(const short8*)(erow + 32 + kb*8);
  int r = isE ? rowp[pc] : (pc - kE);
  int c = isE ? colp[pc] : (pc - kE);
  const unsigned short* xl_ = xl_bf + (size_t)r*kHD + h*64;
  const unsigned short* xr_ = xr_bf + (size_t)c*kHD + h*64;
#pragma unroll
  for (int mt = 0; mt < 4; mt++){
    f.xlu[mt] = *(const uint2*)(xl_ + mt*16 + kb*4);
    f.xru[mt] = *(const uint2*)(xr_ + mt*16 + kb*4);
  }
}

__device__ __forceinline__ void s_comp(int tile, const STile& f,
    const short8 A[4][2], const uint2 attp[4], int lane, int h,
    float* __restrict__ score)
{
  float sc = 0.f;
#pragma unroll
  for (int mt = 0; mt < 4; mt++){
    f32x4 acc = {0.f,0.f,0.f,0.f};
    acc = __builtin_amdgcn_mfma_f32_16x16x32_bf16(A[mt][0], f.b0, acc, 0, 0, 0);
    acc = __builtin_amdgcn_mfma_f32_16x16x32_bf16(A[mt][1], f.b1, acc, 0, 0, 0);
    sc += lrelu02(acc[0] + bf_lo(f.xlu[mt].x) + bf_lo(f.xru[mt].x)) * bf_lo(attp[mt].x);
    sc += lrelu02(acc[1] + bf_hi(f.xlu[mt].x) + bf_hi(f.xru[mt].x)) * bf_hi(attp[mt].x);
    sc += lrelu02(acc[2] + bf_lo(f.xlu[mt].y) + bf_lo(f.xru[mt].y)) * bf_lo(attp[mt].y);
    sc += lrelu02(acc[3] + bf_hi(f.xlu[mt].y) + bf_hi(f.xru[mt].y)) * bf_hi(attp[mt].y);
  }
  sc += __shfl_xor(sc, 16);
  sc += __shfl_xor(sc, 32);
  int wp = tile*16 + lane;
  if (lane < 16 && wp < kEN) score[(size_t)wp*kH + h] = sc;
}

__global__ __launch_bounds__(256) void k_score_mfma(
    const unsigned short* __restrict__ ebf_perm, // [E][64] permuted
    const unsigned short* __restrict__ eloop_bf, // [N][64]
    const unsigned short* __restrict__ xl_bf,    // [N][256]
    const unsigned short* __restrict__ xr_bf,    // [N][256]
    const int* __restrict__ rowp, const int* __restrict__ colp,
    const unsigned short* __restrict__ WeT,      // [256][64] bf16
    const float* __restrict__ att,               // [4][64]
    float* __restrict__ score)                   // [EN][4] permuted
{
  int lane = threadIdx.x & 63;
  int h    = threadIdx.x >> 6;   // wave id == head
  int e16  = lane & 15;
  int kb   = lane >> 4;

  short8 A[4][2];
  uint2 attp[4];
#pragma unroll
  for (int mt = 0; mt < 4; mt++){
    const unsigned short* arow = WeT + (size_t)(h*64 + mt*16 + e16)*64 + kb*8;
    A[mt][0] = *(const short8*)(arow);
    A[mt][1] = *(const short8*)(arow + 32);
    f32x4 av = *(const f32x4*)(att + h*64 + mt*16 + kb*4);
    attp[mt].x = pack_bf2(av[0], av[1]);
    attp[mt].y = pack_bf2(av[2], av[3]);
  }

  constexpr int NT = (kEN + 15)/16;
  const int G = gridDim.x;
  STile fA, fB;
  int t0 = blockIdx.x;
  if (t0 < NT) s_load(t0, fA, e16, kb, h, ebf_perm, eloop_bf, xl_bf, xr_bf, rowp, colp);
  for (int tile = t0; tile < NT; tile += 2*G){
    int t1 = tile + G;
    if (t1 < NT) s_load(t1, fB, e16, kb, h, ebf_perm, eloop_bf, xl_bf, xr_bf, rowp, colp);
    s_comp(tile, fA, A, attp, lane, h, score);
    if (t1 < NT){
      int t2 = tile + 2*G;
      if (t2 < NT) s_load(t2, fA, e16, kb, h, ebf_perm, eloop_bf, xl_bf, xr_bf, rowp, colp);
      s_comp(t1, fB, A, attp, lane, h, score);
    }
  }
}

// ---------------- per-layer: segment softmax weights ----------------
// aw[p][h] = exp(score - m) (unnormalized), inv_s[n][h] = 1/sum.
__global__ void k_segmax(const float* __restrict__ score,
    const int* __restrict__ col_start,
    float* __restrict__ aw, float* __restrict__ inv_s){
  int i = blockIdx.x*256 + threadIdx.x;
  if (i >= kN*kH) return;
  int n = i >> 2, h = i & 3;
  float selfsc = score[(size_t)(kE + n)*kH + h];
  float m = selfsc;
  int s0 = col_start[n], s1 = col_start[n+1];
  for (int p = s0; p < s1; p++)
    m = fmaxf(m, score[(size_t)p*kH + h]);
  float s = expf(selfsc - m);
  aw[(size_t)(kE + n)*kH + h] = s;
  for (int p = s0; p < s1; p++){
    float w = expf(score[(size_t)p*kH + h] - m);
    aw[(size_t)p*kH + h] = w;
    s += w;
  }
  inv_s[i] = 1.f / s;
}

// ---------------- per-layer: aggregate + head-mean + residual + LN + relu --------------
__global__ __launch_bounds__(256) void k_agg_ln(
    const unsigned short* __restrict__ xl_bf, const float* __restrict__ aw,
    const float* __restrict__ inv_s,
    const int* __restrict__ rowp, const int* __restrict__ col_start,
    const float* __restrict__ conv_b, const float* __restrict__ ln_g,
    const float* __restrict__ ln_b, float* __restrict__ x){
  int n = blockIdx.x;
  int j = threadIdx.x, h = j >> 6, d = j & 63;
  float inv = inv_s[n*4 + h];
  float acc = aw[(size_t)(kE + n)*kH + h] * bf2f(xl_bf[(size_t)n*kHD + j]);
  int s0 = col_start[n], s1 = col_start[n+1];
  int p = s0;
  for (; p + 4 <= s1; p += 4){
    int r0 = rowp[p],   r1 = rowp[p+1], r2 = rowp[p+2], r3 = rowp[p+3];
    float a0 = aw[(size_t)p*kH + h],     a1 = aw[(size_t)(p+1)*kH + h];
    float a2 = aw[(size_t)(p+2)*kH + h], a3 = aw[(size_t)(p+3)*kH + h];
    float v0 = bf2f(xl_bf[(size_t)r0*kHD + j]);
    float v1 = bf2f(xl_bf[(size_t)r1*kHD + j]);
    float v2 = bf2f(xl_bf[(size_t)r2*kHD + j]);
    float v3 = bf2f(xl_bf[(size_t)r3*kHD + j]);
    acc += a0*v0; acc += a1*v1; acc += a2*v2; acc += a3*v3;
  }
  for (; p < s1; p++)
    acc += aw[(size_t)p*kH + h] * bf2f(xl_bf[(size_t)rowp[p]*kHD + j]);
  acc *= inv;

  __shared__ float lds[256];
  lds[j] = acc; __syncthreads();
  if (j < 64){
    float upd = (lds[d] + lds[64+d] + lds[128+d] + lds[192+d]) * 0.25f + conv_b[d];
    float y = x[(size_t)n*64 + d] + upd;
    float mu = y;
#pragma unroll
    for (int off = 32; off; off >>= 1) mu += __shfl_xor(mu, off);
    mu *= (1.f/64.f);
    float diff = y - mu;
    float var = diff * diff;
#pragma unroll
    for (int off = 32; off; off >>= 1) var += __shfl_xor(var, off);
    var *= (1.f/64.f);
    float out = diff * rsqrtf(var + 1e-5f) * ln_g[d] + ln_b[d];
    x[(size_t)n*64 + d] = fmaxf(out, 0.f);
  }
}

// ---------------- per-layer: P = x@W1a + b1, Q = x@W1b ----------------
#define PQ_NPB 16
__global__ __launch_bounds__(256) void k_pq(const float* __restrict__ x,
    const float* __restrict__ W1, const float* __restrict__ b1,
    float* __restrict__ P, float* __restrict__ Q){
  __shared__ float xs[PQ_NPB*64];
  int tid = threadIdx.x;
  int j = tid & 63;
  int s = tid >> 6;
  int n0 = blockIdx.x * PQ_NPB;
  for (int i = tid; i < PQ_NPB*64; i += 256){
    int n = n0 + (i >> 6);
    xs[i] = (n < kN) ? x[(size_t)n*64 + (i & 63)] : 0.f;
  }
  __syncthreads();
  float accP[4], accQ[4];
  float b1v = b1[j];
#pragma unroll
  for (int t = 0; t < 4; t++){ accP[t] = b1v; accQ[t] = 0.f; }
  for (int k = 0; k < 64; k++){
    float wa = W1[k*64 + j];
    float wb = W1[(64 + k)*64 + j];
#pragma unroll
    for (int t = 0; t < 4; t++){
      float xv = xs[(s*4 + t)*64 + k];
      accP[t] += xv * wa; accQ[t] += xv * wb;
    }
  }
#pragma unroll
  for (int t = 0; t < 4; t++){
    int n = n0 + s*4 + t;
    if (n < kN){ P[(size_t)n*64 + j] = accP[t]; Q[(size_t)n*64 + j] = accQ[t]; }
  }
}

// ---------------- per-layer: edge MLP via MFMA (bf16 residual) ----------------
// Layers 0,1 (eout_scatter==NULL): residual from ebf_perm, write ebf_perm.
// Layer 2: residual from ebf_perm, scatter f32 to d_out via edge_ids.
__global__ __launch_bounds__(256) void k_mlp_mfma(
    unsigned short* __restrict__ ebf_perm,
    float* __restrict__ eout_scatter,
    const int* __restrict__ edge_ids,
    const float* __restrict__ P, const float* __restrict__ Q,
    const unsigned short* __restrict__ W1cT,  // [64 d][64 k] bf16
    const unsigned short* __restrict__ W2T,   // [64 d][64 k] bf16
    const float* __restrict__ b2,
    const int* __restrict__ rowp, const int* __restrict__ colp)
{
  __shared__ unsigned short Hl[4][1024];      // 2KB per wave
  int lane = threadIdx.x & 63, wv = threadIdx.x >> 6;
  int e16 = lane & 15, g = lane >> 4;
  int swz = (e16 & 7) << 4;
  char* Hw = (char*)Hl[wv];
  bool last = (eout_scatter != nullptr);

  short8 a1[4][2], a2[4][2];
#pragma unroll
  for (int mt = 0; mt < 4; mt++){
#pragma unroll
    for (int c = 0; c < 2; c++){
      a1[mt][c] = *(const short8*)(W1cT + (size_t)(mt*16 + e16)*64 + c*32 + g*8);
      a2[mt][c] = *(const short8*)(W2T  + (size_t)(mt*16 + e16)*64 + c*32 + g*8);
    }
  }
  f32x4 b2v[4];
#pragma unroll
  for (int mt = 0; mt < 4; mt++) b2v[mt] = *(const f32x4*)(b2 + mt*16 + g*4);

  int wid = (blockIdx.x*256 + threadIdx.x) >> 6;
  int nw  = (gridDim.x*256) >> 6;
  for (int tile = wid; tile < kE/16; tile += nw){
    int p = tile*16 + e16;
    int r = rowp[p], c = colp[p];
    const unsigned short* erow = ebf_perm + (size_t)p*64;
    short8 eb0 = *(const short8*)(erow + g*8);
    short8 eb1 = *(const short8*)(erow + 32 + g*8);
    const float* Pr = P + (size_t)r*64;
    const float* Qc = Q + (size_t)c*64;

#pragma unroll
    for (int mt = 0; mt < 4; mt++){
      f32x4 acc = {0.f,0.f,0.f,0.f};
      acc = __builtin_amdgcn_mfma_f32_16x16x32_bf16(a1[mt][0], eb0, acc, 0, 0, 0);
      acc = __builtin_amdgcn_mfma_f32_16x16x32_bf16(a1[mt][1], eb1, acc, 0, 0, 0);
      f32x4 pv = *(const f32x4*)(Pr + mt*16 + g*4);
      f32x4 qv = *(const f32x4*)(Qc + mt*16 + g*4);
      float h0 = fmaxf(acc[0] + pv[0] + qv[0], 0.f);
      float h1 = fmaxf(acc[1] + pv[1] + qv[1], 0.f);
      float h2 = fmaxf(acc[2] + pv[2] + qv[2], 0.f);
      float h3 = fmaxf(acc[3] + pv[3] + qv[3], 0.f);
      uint2 pk; pk.x = pack_bf2(h0, h1); pk.y = pack_bf2(h2, h3);
      *(uint2*)(Hw + (((e16 << 7) + (mt << 5) + (g << 3)) ^ swz)) = pk;
    }
    short8 hb0 = *(const short8*)(Hw + (((e16 << 7)      + (g << 4)) ^ swz));
    short8 hb1 = *(const short8*)(Hw + (((e16 << 7) + 64 + (g << 4)) ^ swz));

    int oe = last ? edge_ids[p] : 0;
#pragma unroll
    for (int mt = 0; mt < 4; mt++){
      f32x4 o = {0.f,0.f,0.f,0.f};
      o = __builtin_amdgcn_mfma_f32_16x16x32_bf16(a2[mt][0], hb0, o, 0, 0, 0);
      o = __builtin_amdgcn_mfma_f32_16x16x32_bf16(a2[mt][1], hb1, o, 0, 0, 0);
      size_t off = (size_t)p*64 + mt*16 + g*4;
      uint2 u = *(const uint2*)(ebf_perm + off);
      f32x4 eo;
      eo[0] = bf_lo(u.x); eo[1] = bf_hi(u.x); eo[2] = bf_lo(u.y); eo[3] = bf_hi(u.y);
      f32x4 ne;
      ne[0] = fmaxf(eo[0] + o[0] + b2v[mt][0], 0.f);
      ne[1] = fmaxf(eo[1] + o[1] + b2v[mt][1], 0.f);
      ne[2] = fmaxf(eo[2] + o[2] + b2v[mt][2], 0.f);
      ne[3] = fmaxf(eo[3] + o[3] + b2v[mt][3], 0.f);
      if (!last){
        uint2 po; po.x = pack_bf2(ne[0], ne[1]); po.y = pack_bf2(ne[2], ne[3]);
        *(uint2*)(ebf_perm + off) = po;
      } else {
        *(f32x4*)(eout_scatter + (size_t)oe*64 + mt*16 + g*4) = ne;
      }
    }
  }
}

// ---------------- host ----------------
extern "C" void kernel_launch(void* const* d_in, const int* in_sizes, int n_in,
                              void* d_out, int out_size, void* d_ws, size_t ws_size,
                              hipStream_t stream) {
  const float* node_feat = (const float*)d_in[0];
  const int*   edge_idx  = (const int*)d_in[1];
  const float* edge_attr = (const float*)d_in[2];
  const float* W_node = (const float*)d_in[3];
  const float* b_node = (const float*)d_in[4];
  const float* W_edge = (const float*)d_in[5];
  const float* b_edge = (const float*)d_in[6];
  const float* Wl   = (const float*)d_in[7];
  const float* bl   = (const float*)d_in[8];
  const float* Wr   = (const float*)d_in[9];
  const float* br   = (const float*)d_in[10];
  const float* We   = (const float*)d_in[11];
  const float* att  = (const float*)d_in[12];
  const float* cvb  = (const float*)d_in[13];
  const float* lng  = (const float*)d_in[14];
  const float* lnb  = (const float*)d_in[15];
  const float* euW1 = (const float*)d_in[16];
  const float* eub1 = (const float*)d_in[17];
  const float* euW2 = (const float*)d_in[18];
  const float* eub2 = (const float*)d_in[19];

  const int* row = edge_idx;
  const int* col = edge_idx + kE;

  float* x = (float*)d_out;                       // N x 64
  float* e_out = (float*)d_out + (size_t)kN*kD;   // E x 64 (written by final scatter)

  char* p = (char*)d_ws;
  auto carve = [&](size_t bytes)->void*{
    void* r = (void*)p;
    p += (bytes + 255) & ~(size_t)255;
    return r;
  };
  unsigned short* xl_bf    = (unsigned short*)carve((size_t)kN*kHD*2);
  unsigned short* xr_bf    = (unsigned short*)carve((size_t)kN*kHD*2);
  float* P      = (float*)carve((size_t)kN*kD*4);
  float* Q      = (float*)carve((size_t)kN*kD*4);
  unsigned short* ebf_perm = (unsigned short*)carve((size_t)kE*kD*2);
  unsigned short* eloop_bf = (unsigned short*)carve((size_t)kN*kD*2);
  unsigned short* WeT      = (unsigned short*)carve((size_t)3*kHD*kD*2);
  unsigned short* W1cT     = (unsigned short*)carve((size_t)3*kD*kD*2);
  unsigned short* W2T      = (unsigned short*)carve((size_t)3*kD*kD*2);
  float* score  = (float*)carve((size_t)kEN*kH*4);
  float* aw     = (float*)carve((size_t)kEN*kH*4);
  float* inv_s  = (float*)carve((size_t)kN*kH*4);
  int* deg      = (int*)carve((size_t)kN*4);
  int* col_start= (int*)carve((size_t)(kN+1)*4);
  int* fill     = (int*)carve((size_t)kN*4);
  int* edge_ids = (int*)carve((size_t)kE*4);
  int* rowp     = (int*)carve((size_t)kE*4);
  int* colp     = (int*)carve((size_t)kE*4);

  // CSR build (graph is layer-invariant)
  hipMemsetAsync(deg, 0, (size_t)kN*4, stream);
  hipMemsetAsync(fill, 0, (size_t)kN*4, stream);
  k_deg<<<(kE+255)/256, 256, 0, stream>>>(col, deg);
  k_scan<<<1, 1024, 0, stream>>>(deg, col_start);
  k_fill<<<(kE+255)/256, 256, 0, stream>>>(col, col_start, fill, edge_ids);
  k_permrc<<<(kE+255)/256, 256, 0, stream>>>(edge_ids, row, col, rowp, colp);

  // weight prepack + initial embeddings
  k_prep<<<192, 256, 0, stream>>>(We, WeT);
  k_prep2<<<48, 256, 0, stream>>>(euW1, euW2, W1cT, W2T);
  k_x0<<<(kN*kD+255)/256, 256, 0, stream>>>(node_feat, W_node, b_node, x);
  k_e0p<<<(int)(((size_t)kE*kD+255)/256), 256, 0, stream>>>(edge_ids, edge_attr, W_edge,
                                                            b_edge, ebf_perm);

  for (int i = 0; i < 3; i++){
    const float* Wl_i  = Wl  + (size_t)i*kD*kHD;
    const float* bl_i  = bl  + (size_t)i*kHD;
    const float* Wr_i  = Wr  + (size_t)i*kD*kHD;
    const float* br_i  = br  + (size_t)i*kHD;
    const float* att_i = att + (size_t)i*kHD;
    const float* cvb_i = cvb + (size_t)i*kD;
    const float* lng_i = lng + (size_t)i*kD;
    const float* lnb_i = lnb + (size_t)i*kD;
    const float* W1_i  = euW1 + (size_t)i*192*64;
    const float* b1_i  = eub1 + (size_t)i*kD;
    const float* b2_i  = eub2 + (size_t)i*kD;
    const unsigned short* WeT_i  = WeT  + (size_t)i*kHD*kD;
    const unsigned short* W1cT_i = W1cT + (size_t)i*kD*kD;
    const unsigned short* W2T_i  = W2T  + (size_t)i*kD*kD;

    k_xlr<<<(kN + XLR_NPB - 1)/XLR_NPB, 256, 0, stream>>>(x, Wl_i, bl_i, Wr_i, br_i,
                                                          xl_bf, xr_bf);
    k_eloop<<<(kN + 3)/4, 256, 0, stream>>>(ebf_perm, col_start, eloop_bf);
    k_score_mfma<<<2048, 256, 0, stream>>>(ebf_perm, eloop_bf, xl_bf, xr_bf,
                                           rowp, colp, WeT_i, att_i, score);
    k_segmax<<<(kN*kH + 255)/256, 256, 0, stream>>>(score, col_start, aw, inv_s);
    k_agg_ln<<<kN, 256, 0, stream>>>(xl_bf, aw, inv_s, rowp, col_start,
                                     cvb_i, lng_i, lnb_i, x);
    k_pq<<<(kN + PQ_NPB - 1)/PQ_NPB, 256, 0, stream>>>(x, W1_i, b1_i, P, Q);
    k_mlp_mfma<<<2048, 256, 0, stream>>>(ebf_perm, (i < 2) ? nullptr : e_out,
                                         edge_ids, P, Q, W1cT_i, W2T_i, b2_i,
                                         rowp, colp);
  }
}